// Round 6
// baseline (325.792 us; speedup 1.0000x reference)
//
#include <hip/hip_runtime.h>
#include <cstddef>
#include <cstdint>

// ---------------------------------------------------------------------------
// MultiheadSelfAttn (b=4, l=2048, d=768, nh=12, hd=64), softmax over QUERY axis.
// cvt -> fused QKV GEMM (dbuf, C^T, bf16 LDS-coalesced epilogue) ->
// LN(bf16 in -> bf16 out, SC2 folded into q) -> stats (no-max exp2 sum) ->
// V transpose (*1/l, PV key-permuted) -> attention out (register-P) ->
// final GEMM (dbuf, C^T, float4 epilogue + bias + residual).
// ---------------------------------------------------------------------------

typedef unsigned short u16;
typedef short  bf16x8 __attribute__((ext_vector_type(8)));   // MFMA A/B frag
typedef float  f32x4  __attribute__((ext_vector_type(4)));   // MFMA C/D frag
typedef unsigned short u16x8 __attribute__((ext_vector_type(8)));
typedef unsigned short u16x4 __attribute__((ext_vector_type(4)));

#define B_   4
#define L_   2048
#define D_   768
#define NH_  12
#define HD_  64
#define M_   (B_*L_)
#define SC2  (0.125f * 1.44269504088896f)   // scale * log2(e), folded into qb

__device__ __forceinline__ float ex2(float x) { return __builtin_amdgcn_exp2f(x); }

__device__ __forceinline__ u16 f2bf(float f) {            // RNE
    union { float f; unsigned u; } v; v.f = f;
    unsigned r = v.u + 0x7FFFu + ((v.u >> 16) & 1u);
    return (u16)(r >> 16);
}
__device__ __forceinline__ float bf2f(u16 b) {
    union { unsigned u; float f; } v; v.u = ((unsigned)b) << 16;
    return v.f;
}
__device__ __forceinline__ unsigned fbits(float f) {
    union { float f; unsigned u; } v; v.f = f; return v.u;
}
// pack two f32 -> (bf16(lo) | bf16(hi)<<16), truncation (P>=0, slack ok)
__device__ __forceinline__ unsigned packbf(float lo, float hi) {
    return __builtin_amdgcn_perm(fbits(hi), fbits(lo), 0x07060302u);
}

// async global->LDS, 16B/lane; LDS dest = wave-uniform base + lane*16.
__device__ __forceinline__ void gld16(const void* g, void* l) {
    __builtin_amdgcn_global_load_lds(
        (const __attribute__((address_space(1))) unsigned*)g,
        (__attribute__((address_space(3))) unsigned*)l, 16, 0, 0);
}

// ---------------------------------------------------------------------------
// fp32 -> bf16 bulk convert
// ---------------------------------------------------------------------------
__global__ __launch_bounds__(256) void cvt_bf16_kernel(
    const float* __restrict__ X, u16* __restrict__ Y, int n8)
{
    int i = blockIdx.x * 256 + threadIdx.x;
    if (i >= n8) return;
    const float4* xp = (const float4*)X + (size_t)i * 2;
    float4 a = xp[0], b = xp[1];
    u16x8 o;
    o[0] = f2bf(a.x); o[1] = f2bf(a.y); o[2] = f2bf(a.z); o[3] = f2bf(a.w);
    o[4] = f2bf(b.x); o[5] = f2bf(b.y); o[6] = f2bf(b.z); o[7] = f2bf(b.w);
    *((u16x8*)Y + i) = o;
}

__global__ __launch_bounds__(256) void cvt4_bf16_kernel(
    const float* __restrict__ W0, const float* __restrict__ W1,
    const float* __restrict__ W2, const float* __restrict__ W3,
    u16* __restrict__ Y0, u16* __restrict__ Y1,
    u16* __restrict__ Y2, u16* __restrict__ Y3, int n8)
{
    const float* X; u16* Y;
    switch (blockIdx.y) {
        case 0: X = W0; Y = Y0; break;
        case 1: X = W1; Y = Y1; break;
        case 2: X = W2; Y = Y2; break;
        default: X = W3; Y = Y3; break;
    }
    int i = blockIdx.x * 256 + threadIdx.x;
    if (i >= n8) return;
    const float4* xp = (const float4*)X + (size_t)i * 2;
    float4 a = xp[0], b = xp[1];
    u16x8 o;
    o[0] = f2bf(a.x); o[1] = f2bf(a.y); o[2] = f2bf(a.z); o[3] = f2bf(a.w);
    o[4] = f2bf(b.x); o[5] = f2bf(b.y); o[6] = f2bf(b.z); o[7] = f2bf(b.w);
    *((u16x8*)Y + i) = o;
}

// ---------------------------------------------------------------------------
// Fused QKV GEMM: A[8192,768] x {Wq,Wk,Wv}^T -> bf16. 128x128 tile, BK=32,
// double-buffered (1 barrier/iter), BK-swizzled LDS, C^T accumulate,
// bf16 epilogue via 32 KB LDS transpose (reuses the dbuf space).
// ---------------------------------------------------------------------------
__global__ __launch_bounds__(256) void gemm_qkv(
    const u16* __restrict__ A,
    const u16* __restrict__ W0, const u16* __restrict__ W1,
    const u16* __restrict__ W2,
    const float* __restrict__ bk, const float* __restrict__ bv,
    u16* __restrict__ q_o, u16* __restrict__ k_o, u16* __restrict__ v_o)
{
    __shared__ __align__(16) u16 lds[16384];   // [A0|A1|B0|B1] 4x8KB -> Ct 32KB
    __shared__ float bs[128];
    const int tid  = threadIdx.x;
    const int lane = tid & 63, w = tid >> 6;
    const int s    = lane & 15, quad = lane >> 4;
    const int seg  = blockIdx.x / 6;
    const int bn   = (blockIdx.x % 6) * 128;
    const int bm   = blockIdx.y * 128;
    const u16* W = (seg == 0) ? W0 : ((seg == 1) ? W1 : W2);
    u16* OUT = (seg == 0) ? q_o : ((seg == 1) ? k_o : v_o);
    const int mh = (w >> 1) * 64, nh = (w & 1) * 64;
    const int wb = tid & ~63;
    const int cq = quad ^ ((s >> 1) & 3);      // swizzled frag chunk

    if (tid < 128)
        bs[tid] = (seg == 1) ? bk[bn + tid] : ((seg == 2) ? bv[bn + tid] : 0.0f);

    f32x4 acc[4][4];   // [j (n-tile)][i (m-tile)], C^T
    #pragma unroll
    for (int j = 0; j < 4; ++j)
        #pragma unroll
        for (int i = 0; i < 4; ++i) acc[j][i] = (f32x4){0.f, 0.f, 0.f, 0.f};

    // stage tile 0 (swizzled: phys chunk (r,cc) holds source chunk cc^((r>>1)&3))
    {
        int c = tid, r = c >> 2, cs = (c & 3) ^ ((r >> 1) & 3);
        gld16(A + (size_t)(bm + r) * D_ + cs * 8, lds + (size_t)wb * 8);
        gld16(W + (size_t)(bn + r) * D_ + cs * 8, lds + 8192 + (size_t)wb * 8);
        c = tid + 256; r = c >> 2; cs = (c & 3) ^ ((r >> 1) & 3);
        gld16(A + (size_t)(bm + r) * D_ + cs * 8, lds + (size_t)(wb + 256) * 8);
        gld16(W + (size_t)(bn + r) * D_ + cs * 8, lds + 8192 + (size_t)(wb + 256) * 8);
    }
    __syncthreads();

    for (int t = 0; t < 24; ++t) {
        const u16* Ab = lds + (t & 1) * 4096;
        const u16* Bb = lds + 8192 + (t & 1) * 4096;
        if (t < 23) {
            const int k0 = (t + 1) * 32;
            u16* Ad = lds + ((t + 1) & 1) * 4096;
            u16* Bd = lds + 8192 + ((t + 1) & 1) * 4096;
            int c = tid, r = c >> 2, cs = (c & 3) ^ ((r >> 1) & 3);
            gld16(A + (size_t)(bm + r) * D_ + k0 + cs * 8, Ad + (size_t)wb * 8);
            gld16(W + (size_t)(bn + r) * D_ + k0 + cs * 8, Bd + (size_t)wb * 8);
            c = tid + 256; r = c >> 2; cs = (c & 3) ^ ((r >> 1) & 3);
            gld16(A + (size_t)(bm + r) * D_ + k0 + cs * 8, Ad + (size_t)(wb + 256) * 8);
            gld16(W + (size_t)(bn + r) * D_ + k0 + cs * 8, Bd + (size_t)(wb + 256) * 8);
        }
        bf16x8 af[4], bf[4];
        #pragma unroll
        for (int i = 0; i < 4; ++i)
            af[i] = *(const bf16x8*)(Ab + (mh + i * 16 + s) * 32 + cq * 8);
        #pragma unroll
        for (int j = 0; j < 4; ++j)
            bf[j] = *(const bf16x8*)(Bb + (nh + j * 16 + s) * 32 + cq * 8);
        #pragma unroll
        for (int j = 0; j < 4; ++j)
            #pragma unroll
            for (int i = 0; i < 4; ++i)
                acc[j][i] = __builtin_amdgcn_mfma_f32_16x16x32_bf16(
                    bf[j], af[i], acc[j][i], 0, 0, 0);   // C^T: rows=n, cols=m
        __syncthreads();   // prefetch landed + this iter's ds_reads complete
    }
    // epilogue: bf16 + bias -> Ct[m][128] (chunk ^ (m&15)) -> coalesced store
    u16* Ct = lds;
    #pragma unroll
    for (int j = 0; j < 4; ++j) {
        const int n0 = nh + j * 16 + quad * 4;
        const f32x4 b4 = *(const f32x4*)(bs + n0);
        const int cn = n0 >> 3, off = n0 & 7;
        #pragma unroll
        for (int i = 0; i < 4; ++i) {
            const int m = mh + i * 16 + s;
            u16x4 ov;
            #pragma unroll
            for (int r = 0; r < 4; ++r) ov[r] = f2bf(acc[j][i][r] + b4[r]);
            *(u16x4*)(Ct + m * 128 + ((cn ^ (m & 15)) * 8) + off) = ov;
        }
    }
    __syncthreads();
    {
        const int m = tid >> 1, half = tid & 1;
        u16* dst = OUT + (size_t)(bm + m) * D_ + bn + half * 64;
        #pragma unroll
        for (int cc = 0; cc < 8; ++cc) {
            const int cn = half * 8 + cc;
            u16x8 v = *(const u16x8*)(Ct + m * 128 + ((cn ^ (m & 15)) * 8));
            *(u16x8*)(dst + cc * 8) = v;
        }
    }
}

// ---------------------------------------------------------------------------
// Final GEMM: out = ob @ Wo^T + bo + x (fp32 out). dbuf + C^T + float4 stores.
// ---------------------------------------------------------------------------
__global__ __launch_bounds__(256) void gemm_final(
    const u16* __restrict__ A, const u16* __restrict__ W,
    const float* __restrict__ bias, const float* __restrict__ resid,
    float* __restrict__ outf)
{
    __shared__ __align__(16) u16 lds[16384];
    const int tid  = threadIdx.x;
    const int lane = tid & 63, w = tid >> 6;
    const int s    = lane & 15, quad = lane >> 4;
    const int bm   = blockIdx.y * 128, bn = blockIdx.x * 128;
    const int mh   = (w >> 1) * 64, nh = (w & 1) * 64;
    const int wb   = tid & ~63;
    const int cq   = quad ^ ((s >> 1) & 3);
    f32x4 acc[4][4];
    #pragma unroll
    for (int j = 0; j < 4; ++j)
        #pragma unroll
        for (int i = 0; i < 4; ++i) acc[j][i] = (f32x4){0.f, 0.f, 0.f, 0.f};

    {
        int c = tid, r = c >> 2, cs = (c & 3) ^ ((r >> 1) & 3);
        gld16(A + (size_t)(bm + r) * D_ + cs * 8, lds + (size_t)wb * 8);
        gld16(W + (size_t)(bn + r) * D_ + cs * 8, lds + 8192 + (size_t)wb * 8);
        c = tid + 256; r = c >> 2; cs = (c & 3) ^ ((r >> 1) & 3);
        gld16(A + (size_t)(bm + r) * D_ + cs * 8, lds + (size_t)(wb + 256) * 8);
        gld16(W + (size_t)(bn + r) * D_ + cs * 8, lds + 8192 + (size_t)(wb + 256) * 8);
    }
    __syncthreads();

    for (int t = 0; t < 24; ++t) {
        const u16* Ab = lds + (t & 1) * 4096;
        const u16* Bb = lds + 8192 + (t & 1) * 4096;
        if (t < 23) {
            const int k0 = (t + 1) * 32;
            u16* Ad = lds + ((t + 1) & 1) * 4096;
            u16* Bd = lds + 8192 + ((t + 1) & 1) * 4096;
            int c = tid, r = c >> 2, cs = (c & 3) ^ ((r >> 1) & 3);
            gld16(A + (size_t)(bm + r) * D_ + k0 + cs * 8, Ad + (size_t)wb * 8);
            gld16(W + (size_t)(bn + r) * D_ + k0 + cs * 8, Bd + (size_t)wb * 8);
            c = tid + 256; r = c >> 2; cs = (c & 3) ^ ((r >> 1) & 3);
            gld16(A + (size_t)(bm + r) * D_ + k0 + cs * 8, Ad + (size_t)(wb + 256) * 8);
            gld16(W + (size_t)(bn + r) * D_ + k0 + cs * 8, Bd + (size_t)(wb + 256) * 8);
        }
        bf16x8 af[4], bf[4];
        #pragma unroll
        for (int i = 0; i < 4; ++i)
            af[i] = *(const bf16x8*)(Ab + (mh + i * 16 + s) * 32 + cq * 8);
        #pragma unroll
        for (int j = 0; j < 4; ++j)
            bf[j] = *(const bf16x8*)(Bb + (nh + j * 16 + s) * 32 + cq * 8);
        #pragma unroll
        for (int j = 0; j < 4; ++j)
            #pragma unroll
            for (int i = 0; i < 4; ++i)
                acc[j][i] = __builtin_amdgcn_mfma_f32_16x16x32_bf16(
                    bf[j], af[i], acc[j][i], 0, 0, 0);
        __syncthreads();
    }
    // epilogue: lane holds 4 consecutive n at fixed m -> float4 direct
    #pragma unroll
    for (int j = 0; j < 4; ++j) {
        const int n0 = nh + j * 16 + quad * 4;
        const float4 b4 = *(const float4*)(bias + bn + n0);
        #pragma unroll
        for (int i = 0; i < 4; ++i) {
            const int m = mh + i * 16 + s;
            const size_t base = (size_t)(bm + m) * D_ + bn + n0;
            const float4 rs = *(const float4*)(resid + base);
            float4 o;
            o.x = acc[j][i][0] + b4.x + rs.x;
            o.y = acc[j][i][1] + b4.y + rs.y;
            o.z = acc[j][i][2] + b4.z + rs.z;
            o.w = acc[j][i][3] + b4.w + rs.w;
            *(float4*)(outf + base) = o;
        }
    }
}

// ---------------------------------------------------------------------------
// Row LayerNorm (pop var, eps 1e-5) * gamma * scale, bf16 in -> bf16 out.
// ---------------------------------------------------------------------------
__global__ __launch_bounds__(256) void ln_bf16(
    const u16* __restrict__ X, const float* __restrict__ gamma,
    u16* __restrict__ Y, float scale)
{
    const int row = blockIdx.x;
    const u16* x = X + (size_t)row * D_;
    const int tid = threadIdx.x;
    float v[3];
    float lsum = 0.f, lsq = 0.f;
    #pragma unroll
    for (int e = 0; e < 3; ++e) {
        float t = bf2f(x[tid + e * 256]);
        v[e] = t; lsum += t; lsq += t * t;
    }
    #pragma unroll
    for (int off = 32; off > 0; off >>= 1) {
        lsum += __shfl_down(lsum, off);
        lsq  += __shfl_down(lsq,  off);
    }
    __shared__ float s1[4], s2[4];
    const int wv = tid >> 6, lane = tid & 63;
    if (lane == 0) { s1[wv] = lsum; s2[wv] = lsq; }
    __syncthreads();
    const float sum = s1[0] + s1[1] + s1[2] + s1[3];
    const float sq  = s2[0] + s2[1] + s2[2] + s2[3];
    const float mu  = sum * (1.0f / D_);
    const float var = sq * (1.0f / D_) - mu * mu;
    const float inv = rsqrtf(var + 1e-5f) * scale;
    #pragma unroll
    for (int e = 0; e < 3; ++e) {
        int c = tid + e * 256;
        Y[(size_t)row * D_ + c] = f2bf((v[e] - mu) * inv * gamma[c]);
    }
}

// ---------------------------------------------------------------------------
// Pass A: per-key l = sum_q exp2(s~[q,k]) (NO max: QK-norm bounds scores).
// ---------------------------------------------------------------------------
__global__ __launch_bounds__(256) void attn_stats(
    const u16* __restrict__ Qb, const u16* __restrict__ Kb,
    float* __restrict__ Rl)
{
    __shared__ __align__(16) u16 Ks[128 * 64];       // 16 KB
    __shared__ __align__(16) u16 Qs[2][128 * 64];    // 32 KB dbuf
    __shared__ float lbuf[4][64];
    const int tid  = threadIdx.x;
    const int lane = tid & 63, w = tid >> 6;
    const int s    = lane & 15, quad = lane >> 4;
    const int s7   = s & 7;
    const int bh   = blockIdx.y;
    const int b    = bh / NH_, h = bh % NH_;
    const int kbase = blockIdx.x * 128;
    const u16* Qg = Qb + (size_t)b * L_ * D_ + h * HD_;
    const u16* Kg = Kb + (size_t)b * L_ * D_ + h * HD_;
    const int mh = (w >> 1) * 64;   // key half
    const int nh = (w & 1) * 64;    // query half
    const int wb = tid & ~63;

    #pragma unroll
    for (int c0 = 0; c0 < 1024; c0 += 256) {
        int c = c0 + tid, r = c >> 3, cc = (c & 7) ^ (r & 7);
        gld16(Kg + (size_t)(kbase + r) * D_ + cc * 8, Ks + (size_t)(c0 + wb) * 8);
        gld16(Qg + (size_t)r * D_ + cc * 8, Qs[0] + (size_t)(c0 + wb) * 8);
    }
    __syncthreads();
    bf16x8 kf[2][4];
    #pragma unroll
    for (int kk = 0; kk < 2; ++kk)
        #pragma unroll
        for (int i = 0; i < 4; ++i)
            kf[kk][i] = *(const bf16x8*)(Ks + (mh + i * 16 + s) * 64 +
                                         ((kk * 4 + quad) ^ s7) * 8);
    float lacc[4][4];
    #pragma unroll
    for (int i = 0; i < 4; ++i)
        #pragma unroll
        for (int r = 0; r < 4; ++r) lacc[i][r] = 0.f;

    for (int t = 0; t < 16; ++t) {
        if (t < 15) {
            const int qn = (t + 1) * 128;
            u16* Qd = Qs[(t + 1) & 1];
            #pragma unroll
            for (int c0 = 0; c0 < 1024; c0 += 256) {
                int c = c0 + tid, r = c >> 3, cc = (c & 7) ^ (r & 7);
                gld16(Qg + (size_t)(qn + r) * D_ + cc * 8, Qd + (size_t)(c0 + wb) * 8);
            }
        }
        const u16* Qt = Qs[t & 1];
        f32x4 acc[4][4];
        #pragma unroll
        for (int i = 0; i < 4; ++i)
            #pragma unroll
            for (int j = 0; j < 4; ++j) acc[i][j] = (f32x4){0.f, 0.f, 0.f, 0.f};
        #pragma unroll
        for (int kk = 0; kk < 2; ++kk) {
            bf16x8 bf[4];
            #pragma unroll
            for (int j = 0; j < 4; ++j)
                bf[j] = *(const bf16x8*)(Qt + (nh + j * 16 + s) * 64 +
                                         ((kk * 4 + quad) ^ s7) * 8);
            #pragma unroll
            for (int i = 0; i < 4; ++i)
                #pragma unroll
                for (int j = 0; j < 4; ++j)
                    acc[i][j] = __builtin_amdgcn_mfma_f32_16x16x32_bf16(
                        kf[kk][i], bf[j], acc[i][j], 0, 0, 0);
        }
        #pragma unroll
        for (int i = 0; i < 4; ++i)
            #pragma unroll
            for (int r = 0; r < 4; ++r) {
                float l0 = ex2(acc[i][0][r]) + ex2(acc[i][1][r]);
                float l1 = ex2(acc[i][2][r]) + ex2(acc[i][3][r]);
                lacc[i][r] += l0 + l1;
            }
        __syncthreads();
    }
    #pragma unroll
    for (int i = 0; i < 4; ++i)
        #pragma unroll
        for (int r = 0; r < 4; ++r) {
            float v = lacc[i][r];
            #pragma unroll
            for (int d2 = 1; d2 < 16; d2 <<= 1) v += __shfl_xor(v, d2);
            lacc[i][r] = v;
        }
    if (s == 0) {
        #pragma unroll
        for (int i = 0; i < 4; ++i)
            #pragma unroll
            for (int r = 0; r < 4; ++r)
                lbuf[w][i * 16 + quad * 4 + r] = lacc[i][r];
    }
    __syncthreads();
    if (tid < 128) {
        int kh = tid >> 6, kl = tid & 63;
        float l = lbuf[kh * 2][kl] + lbuf[kh * 2 + 1][kl];
        Rl[(size_t)bh * L_ + kbase + tid] = 1.0f / l;
    }
}

// ---------------------------------------------------------------------------
// V transpose + fold 1/l + PV key-permutation (p = ((a>>2)&3)*8+((a>>4)&1)*4+(a&3))
// ---------------------------------------------------------------------------
__global__ __launch_bounds__(256) void transpose_v_scaled(
    const u16* __restrict__ Vb, const float* __restrict__ Rl,
    u16* __restrict__ Vt)
{
    const int l0 = blockIdx.x * 64, h = blockIdx.y, b = blockIdx.z;
    const int bh = b * NH_ + h;
    __shared__ __align__(16) u16 Ts[64][72];
    const int tid = threadIdx.x;
    #pragma unroll
    for (int c = tid; c < 512; c += 256) {
        int r = c >> 3, cc = c & 7;
        u16x8 val = *(const u16x8*)(Vb + (size_t)(b * L_ + l0 + r) * D_ + h * HD_ + cc * 8);
        const float rl = Rl[(size_t)bh * L_ + l0 + r];
        #pragma unroll
        for (int e = 0; e < 8; ++e) val[e] = f2bf(bf2f(val[e]) * rl);
        *(u16x8*)(&Ts[r][cc * 8]) = val;
    }
    __syncthreads();
    const int d = tid >> 2, lc = (tid & 3) * 16;
    u16 tmp[16];
    #pragma unroll
    for (int e = 0; e < 16; ++e) tmp[e] = Ts[lc + e][d];
    u16* dst = Vt + ((size_t)bh * HD_ + d) * L_ + l0 + (lc & 32) + ((lc >> 4) & 1) * 4;
    #pragma unroll
    for (int qd = 0; qd < 4; ++qd) {
        u16x4 o;
        #pragma unroll
        for (int e = 0; e < 4; ++e) o[e] = tmp[qd * 4 + e];
        *(u16x4*)(dst + qd * 8) = o;
    }
}

// ---------------------------------------------------------------------------
// Pass B: O^T = V'^T · P^T, P = exp2(s~) in registers. 256 q/block.
// ---------------------------------------------------------------------------
__global__ __launch_bounds__(256, 2) void attn_out(
    const u16* __restrict__ Qb, const u16* __restrict__ Kb,
    const u16* __restrict__ Vt, u16* __restrict__ Ob)
{
    __shared__ __align__(16) u16 Qs[256 * 64];     // 32 KB: Q staging -> O epilogue
    __shared__ __align__(16) u16 Ks[2][64 * 64];   // 16 KB dbuf
    __shared__ __align__(16) u16 Vts[2][64 * 64];  // 16 KB dbuf
    const int tid  = threadIdx.x;
    const int lane = tid & 63, w = tid >> 6;
    const int s    = lane & 15, quad = lane >> 4;
    const int s7   = s & 7;
    const int bh   = blockIdx.y;
    const int b    = bh / NH_, h = bh % NH_;
    const int qbase = blockIdx.x * 256;
    const int qw   = w * 64;
    const u16* Qg = Qb + (size_t)b * L_ * D_ + h * HD_;
    const u16* Kg = Kb + (size_t)b * L_ * D_ + h * HD_;
    const u16* Vg = Vt + (size_t)bh * HD_ * L_;
    const int wb = tid & ~63;

    #pragma unroll
    for (int c0 = 0; c0 < 2048; c0 += 256) {
        int c = c0 + tid, r = c >> 3, cc = (c & 7) ^ (r & 7);
        gld16(Qg + (size_t)(qbase + r) * D_ + cc * 8, Qs + (size_t)(c0 + wb) * 8);
    }
    {
        int c = tid, r = c >> 3, cc = (c & 7) ^ (r & 7);
        gld16(Kg + (size_t)r * D_ + cc * 8, Ks[0] + (size_t)wb * 8);
        gld16(Vg + (size_t)r * L_ + cc * 8, Vts[0] + (size_t)wb * 8);
        c = tid + 256; r = c >> 3; cc = (c & 7) ^ (r & 7);
        gld16(Kg + (size_t)r * D_ + cc * 8, Ks[0] + (size_t)(wb + 256) * 8);
        gld16(Vg + (size_t)r * L_ + cc * 8, Vts[0] + (size_t)(wb + 256) * 8);
    }
    __syncthreads();
    bf16x8 qf[2][4];
    #pragma unroll
    for (int kk = 0; kk < 2; ++kk)
        #pragma unroll
        for (int j = 0; j < 4; ++j)
            qf[kk][j] = *(const bf16x8*)(Qs + (qw + j * 16 + s) * 64 +
                                         ((kk * 4 + quad) ^ s7) * 8);
    f32x4 acc_o[4][4];
    #pragma unroll
    for (int i = 0; i < 4; ++i)
        #pragma unroll
        for (int j = 0; j < 4; ++j) acc_o[i][j] = (f32x4){0.f, 0.f, 0.f, 0.f};

    for (int t = 0; t < 32; ++t) {
        const u16* Kt  = Ks[t & 1];
        const u16* Vtt = Vts[t & 1];
        if (t < 31) {
            const int kn = (t + 1) * 64;
            u16* Kd = Ks[(t + 1) & 1];
            u16* Vd = Vts[(t + 1) & 1];
            int c = tid, r = c >> 3, cc = (c & 7) ^ (r & 7);
            gld16(Kg + (size_t)(kn + r) * D_ + cc * 8, Kd + (size_t)wb * 8);
            gld16(Vg + (size_t)r * L_ + kn + cc * 8,   Vd + (size_t)wb * 8);
            c = tid + 256; r = c >> 3; cc = (c & 7) ^ (r & 7);
            gld16(Kg + (size_t)(kn + r) * D_ + cc * 8, Kd + (size_t)(wb + 256) * 8);
            gld16(Vg + (size_t)r * L_ + kn + cc * 8,   Vd + (size_t)(wb + 256) * 8);
        }
        f32x4 acc_s[4][4];
        #pragma unroll
        for (int i = 0; i < 4; ++i)
            #pragma unroll
            for (int j = 0; j < 4; ++j) acc_s[i][j] = (f32x4){0.f, 0.f, 0.f, 0.f};
        #pragma unroll
        for (int kk = 0; kk < 2; ++kk) {
            bf16x8 kfr[4];
            #pragma unroll
            for (int i = 0; i < 4; ++i)
                kfr[i] = *(const bf16x8*)(Kt + (i * 16 + s) * 64 +
                                          ((kk * 4 + quad) ^ s7) * 8);
            #pragma unroll
            for (int i = 0; i < 4; ++i)
                #pragma unroll
                for (int j = 0; j < 4; ++j)
                    acc_s[i][j] = __builtin_amdgcn_mfma_f32_16x16x32_bf16(
                        kfr[i], qf[kk][j], acc_s[i][j], 0, 0, 0);
        }
        unsigned pk[4][4][2];
        #pragma unroll
        for (int i = 0; i < 4; ++i)
            #pragma unroll
            for (int j = 0; j < 4; ++j) {
                float p0 = ex2(acc_s[i][j][0]), p1 = ex2(acc_s[i][j][1]);
                float p2 = ex2(acc_s[i][j][2]), p3 = ex2(acc_s[i][j][3]);
                pk[i][j][0] = packbf(p0, p1);
                pk[i][j][1] = packbf(p2, p3);
            }
        #pragma unroll
        for (int kk = 0; kk < 2; ++kk) {
            bf16x8 av[4];
            #pragma unroll
            for (int i = 0; i < 4; ++i)
                av[i] = *(const bf16x8*)(Vtt + (i * 16 + s) * 64 +
                                         ((kk * 4 + quad) ^ s7) * 8);
            #pragma unroll
            for (int j = 0; j < 4; ++j) {
                union { unsigned u[4]; bf16x8 v; } bu;
                bu.u[0] = pk[2 * kk][j][0];
                bu.u[1] = pk[2 * kk][j][1];
                bu.u[2] = pk[2 * kk + 1][j][0];
                bu.u[3] = pk[2 * kk + 1][j][1];
                #pragma unroll
                for (int i = 0; i < 4; ++i)
                    acc_o[i][j] = __builtin_amdgcn_mfma_f32_16x16x32_bf16(
                        av[i], bu.v, acc_o[i][j], 0, 0, 0);
            }
        }
        __syncthreads();
    }
    #pragma unroll
    for (int i = 0; i < 4; ++i) {
        const int dchunk = i * 2 + (quad >> 1), doff = (quad & 1) * 4;
        #pragma unroll
        for (int j = 0; j < 4; ++j) {
            const int q = qw + j * 16 + s;
            u16x4 ov;
            #pragma unroll
            for (int r = 0; r < 4; ++r) ov[r] = f2bf(acc_o[i][j][r]);
            *(u16x4*)(Qs + q * 64 + (dchunk ^ s7) * 8 + doff) = ov;
        }
    }
    __syncthreads();
    {
        const int q7 = tid & 7;
        u16* dst = Ob + (size_t)(b * L_ + qbase + tid) * D_ + h * HD_;
        #pragma unroll
        for (int c = 0; c < 8; ++c) {
            u16x8 v = *(const u16x8*)(Qs + tid * 64 + ((c ^ q7) * 8));
            *(u16x8*)(dst + c * 8) = v;
        }
    }
}

// ---------------------------------------------------------------------------
extern "C" void kernel_launch(void* const* d_in, const int* in_sizes, int n_in,
                              void* d_out, int out_size, void* d_ws, size_t ws_size,
                              hipStream_t stream)
{
    const float* x  = (const float*)d_in[0];
    const float* Wq = (const float*)d_in[1];
    const float* Wk = (const float*)d_in[2];
    const float* bk = (const float*)d_in[3];
    const float* Wv = (const float*)d_in[4];
    const float* bv = (const float*)d_in[5];
    const float* gq = (const float*)d_in[6];
    const float* gk = (const float*)d_in[7];
    const float* Wo = (const float*)d_in[8];
    const float* bo = (const float*)d_in[9];
    float* out = (float*)d_out;

    char* p = (char*)d_ws;
    u16* xb   = (u16*)p;  p += (size_t)M_ * D_ * 2;
    u16* qpre = (u16*)p;  p += (size_t)M_ * D_ * 2;   // ob aliases after LN
    u16* kpre = (u16*)p;  p += (size_t)M_ * D_ * 2;   // vt aliases after LN
    u16* vb   = (u16*)p;  p += (size_t)M_ * D_ * 2;
    u16* qb   = (u16*)p;  p += (size_t)M_ * D_ * 2;
    u16* kb   = (u16*)p;  p += (size_t)M_ * D_ * 2;
    u16* wqb  = (u16*)p;  p += (size_t)D_ * D_ * 2;
    u16* wkb  = (u16*)p;  p += (size_t)D_ * D_ * 2;
    u16* wvb  = (u16*)p;  p += (size_t)D_ * D_ * 2;
    u16* wob  = (u16*)p;  p += (size_t)D_ * D_ * 2;
    float* Rl = (float*)p; p += (size_t)B_ * NH_ * L_ * 4;
    u16* ob = qpre;   // dead after LN
    u16* vt = kpre;   // dead after LN

    const int nX = M_ * D_, nW = D_ * D_;
    cvt_bf16_kernel<<<nX / 2048, 256, 0, stream>>>(x, xb, nX / 8);
    cvt4_bf16_kernel<<<dim3(nW / 2048, 4), 256, 0, stream>>>(
        Wq, Wk, Wv, Wo, wqb, wkb, wvb, wob, nW / 8);

    gemm_qkv<<<dim3(18, M_ / 128), 256, 0, stream>>>(
        xb, wqb, wkb, wvb, bk, bv, qpre, kpre, vb);

    ln_bf16<<<M_, 256, 0, stream>>>(qpre, gq, qb, SC2);
    ln_bf16<<<M_, 256, 0, stream>>>(kpre, gk, kb, 1.0f);

    dim3 sgrid(L_ / 128, B_ * NH_);   // (16, 48)
    attn_stats<<<sgrid, 256, 0, stream>>>(qb, kb, Rl);
    transpose_v_scaled<<<dim3(L_ / 64, NH_, B_), 256, 0, stream>>>(vb, Rl, vt);
    dim3 ogrid(L_ / 256, B_ * NH_);   // (8, 48)
    attn_out<<<ogrid, 256, 0, stream>>>(qb, kb, vt, ob);

    gemm_final<<<dim3(D_ / 128, M_ / 128), 256, 0, stream>>>(ob, wob, bo, x, out);
}

// Round 7
// 308.761 us; speedup vs baseline: 1.0552x; 1.0552x over previous
//
#include <hip/hip_runtime.h>
#include <cstddef>
#include <cstdint>

// ---------------------------------------------------------------------------
// MultiheadSelfAttn (b=4, l=2048, d=768, nh=12, hd=64), softmax over QUERY axis.
// cvt -> fused QKV GEMM (dbuf, C^T, bf16 LDS-coalesced epilogue) ->
// LN(bf16 in -> bf16 out, SC2 folded into q) -> stats (no-max exp2 sum) ->
// V transpose (*1/l, PV key-permuted) -> attention out (register-P, 128q
// blocks for 3 blocks/CU occupancy) -> final GEMM (dbuf, C^T, float4 epilogue).
// ---------------------------------------------------------------------------

typedef unsigned short u16;
typedef short  bf16x8 __attribute__((ext_vector_type(8)));   // MFMA A/B frag
typedef float  f32x4  __attribute__((ext_vector_type(4)));   // MFMA C/D frag
typedef unsigned short u16x8 __attribute__((ext_vector_type(8)));
typedef unsigned short u16x4 __attribute__((ext_vector_type(4)));

#define B_   4
#define L_   2048
#define D_   768
#define NH_  12
#define HD_  64
#define M_   (B_*L_)
#define SC2  (0.125f * 1.44269504088896f)   // scale * log2(e), folded into qb

__device__ __forceinline__ float ex2(float x) { return __builtin_amdgcn_exp2f(x); }

__device__ __forceinline__ u16 f2bf(float f) {            // RNE
    union { float f; unsigned u; } v; v.f = f;
    unsigned r = v.u + 0x7FFFu + ((v.u >> 16) & 1u);
    return (u16)(r >> 16);
}
__device__ __forceinline__ float bf2f(u16 b) {
    union { unsigned u; float f; } v; v.u = ((unsigned)b) << 16;
    return v.f;
}
__device__ __forceinline__ unsigned fbits(float f) {
    union { float f; unsigned u; } v; v.f = f; return v.u;
}
// pack two f32 -> (bf16(lo) | bf16(hi)<<16), truncation (P>=0, slack ok)
__device__ __forceinline__ unsigned packbf(float lo, float hi) {
    return __builtin_amdgcn_perm(fbits(hi), fbits(lo), 0x07060302u);
}

// async global->LDS, 16B/lane; LDS dest = wave-uniform base + lane*16.
__device__ __forceinline__ void gld16(const void* g, void* l) {
    __builtin_amdgcn_global_load_lds(
        (const __attribute__((address_space(1))) unsigned*)g,
        (__attribute__((address_space(3))) unsigned*)l, 16, 0, 0);
}

// ---------------------------------------------------------------------------
// fp32 -> bf16 bulk convert
// ---------------------------------------------------------------------------
__global__ __launch_bounds__(256) void cvt_bf16_kernel(
    const float* __restrict__ X, u16* __restrict__ Y, int n8)
{
    int i = blockIdx.x * 256 + threadIdx.x;
    if (i >= n8) return;
    const float4* xp = (const float4*)X + (size_t)i * 2;
    float4 a = xp[0], b = xp[1];
    u16x8 o;
    o[0] = f2bf(a.x); o[1] = f2bf(a.y); o[2] = f2bf(a.z); o[3] = f2bf(a.w);
    o[4] = f2bf(b.x); o[5] = f2bf(b.y); o[6] = f2bf(b.z); o[7] = f2bf(b.w);
    *((u16x8*)Y + i) = o;
}

__global__ __launch_bounds__(256) void cvt4_bf16_kernel(
    const float* __restrict__ W0, const float* __restrict__ W1,
    const float* __restrict__ W2, const float* __restrict__ W3,
    u16* __restrict__ Y0, u16* __restrict__ Y1,
    u16* __restrict__ Y2, u16* __restrict__ Y3, int n8)
{
    const float* X; u16* Y;
    switch (blockIdx.y) {
        case 0: X = W0; Y = Y0; break;
        case 1: X = W1; Y = Y1; break;
        case 2: X = W2; Y = Y2; break;
        default: X = W3; Y = Y3; break;
    }
    int i = blockIdx.x * 256 + threadIdx.x;
    if (i >= n8) return;
    const float4* xp = (const float4*)X + (size_t)i * 2;
    float4 a = xp[0], b = xp[1];
    u16x8 o;
    o[0] = f2bf(a.x); o[1] = f2bf(a.y); o[2] = f2bf(a.z); o[3] = f2bf(a.w);
    o[4] = f2bf(b.x); o[5] = f2bf(b.y); o[6] = f2bf(b.z); o[7] = f2bf(b.w);
    *((u16x8*)Y + i) = o;
}

// ---------------------------------------------------------------------------
// Fused QKV GEMM: A[8192,768] x {Wq,Wk,Wv}^T -> bf16. 128x128 tile, BK=32,
// double-buffered (1 barrier/iter), BK-swizzled LDS, C^T accumulate,
// bf16 epilogue via 32 KB LDS transpose (reuses the dbuf space).
// ---------------------------------------------------------------------------
__global__ __launch_bounds__(256) void gemm_qkv(
    const u16* __restrict__ A,
    const u16* __restrict__ W0, const u16* __restrict__ W1,
    const u16* __restrict__ W2,
    const float* __restrict__ bk, const float* __restrict__ bv,
    u16* __restrict__ q_o, u16* __restrict__ k_o, u16* __restrict__ v_o)
{
    __shared__ __align__(16) u16 lds[16384];   // [A0|A1|B0|B1] 4x8KB -> Ct 32KB
    __shared__ float bs[128];
    const int tid  = threadIdx.x;
    const int lane = tid & 63, w = tid >> 6;
    const int s    = lane & 15, quad = lane >> 4;
    const int seg  = blockIdx.x / 6;
    const int bn   = (blockIdx.x % 6) * 128;
    const int bm   = blockIdx.y * 128;
    const u16* W = (seg == 0) ? W0 : ((seg == 1) ? W1 : W2);
    u16* OUT = (seg == 0) ? q_o : ((seg == 1) ? k_o : v_o);
    const int mh = (w >> 1) * 64, nh = (w & 1) * 64;
    const int wb = tid & ~63;
    const int cq = quad ^ ((s >> 1) & 3);      // swizzled frag chunk

    if (tid < 128)
        bs[tid] = (seg == 1) ? bk[bn + tid] : ((seg == 2) ? bv[bn + tid] : 0.0f);

    f32x4 acc[4][4];   // [j (n-tile)][i (m-tile)], C^T
    #pragma unroll
    for (int j = 0; j < 4; ++j)
        #pragma unroll
        for (int i = 0; i < 4; ++i) acc[j][i] = (f32x4){0.f, 0.f, 0.f, 0.f};

    {
        int c = tid, r = c >> 2, cs = (c & 3) ^ ((r >> 1) & 3);
        gld16(A + (size_t)(bm + r) * D_ + cs * 8, lds + (size_t)wb * 8);
        gld16(W + (size_t)(bn + r) * D_ + cs * 8, lds + 8192 + (size_t)wb * 8);
        c = tid + 256; r = c >> 2; cs = (c & 3) ^ ((r >> 1) & 3);
        gld16(A + (size_t)(bm + r) * D_ + cs * 8, lds + (size_t)(wb + 256) * 8);
        gld16(W + (size_t)(bn + r) * D_ + cs * 8, lds + 8192 + (size_t)(wb + 256) * 8);
    }
    __syncthreads();

    for (int t = 0; t < 24; ++t) {
        const u16* Ab = lds + (t & 1) * 4096;
        const u16* Bb = lds + 8192 + (t & 1) * 4096;
        if (t < 23) {
            const int k0 = (t + 1) * 32;
            u16* Ad = lds + ((t + 1) & 1) * 4096;
            u16* Bd = lds + 8192 + ((t + 1) & 1) * 4096;
            int c = tid, r = c >> 2, cs = (c & 3) ^ ((r >> 1) & 3);
            gld16(A + (size_t)(bm + r) * D_ + k0 + cs * 8, Ad + (size_t)wb * 8);
            gld16(W + (size_t)(bn + r) * D_ + k0 + cs * 8, Bd + (size_t)wb * 8);
            c = tid + 256; r = c >> 2; cs = (c & 3) ^ ((r >> 1) & 3);
            gld16(A + (size_t)(bm + r) * D_ + k0 + cs * 8, Ad + (size_t)(wb + 256) * 8);
            gld16(W + (size_t)(bn + r) * D_ + k0 + cs * 8, Bd + (size_t)(wb + 256) * 8);
        }
        bf16x8 af[4], bf[4];
        #pragma unroll
        for (int i = 0; i < 4; ++i)
            af[i] = *(const bf16x8*)(Ab + (mh + i * 16 + s) * 32 + cq * 8);
        #pragma unroll
        for (int j = 0; j < 4; ++j)
            bf[j] = *(const bf16x8*)(Bb + (nh + j * 16 + s) * 32 + cq * 8);
        #pragma unroll
        for (int j = 0; j < 4; ++j)
            #pragma unroll
            for (int i = 0; i < 4; ++i)
                acc[j][i] = __builtin_amdgcn_mfma_f32_16x16x32_bf16(
                    bf[j], af[i], acc[j][i], 0, 0, 0);   // C^T: rows=n, cols=m
        __syncthreads();
    }
    // epilogue: bf16 + bias -> Ct[m][128] (chunk ^ (m&15)) -> coalesced store
    u16* Ct = lds;
    #pragma unroll
    for (int j = 0; j < 4; ++j) {
        const int n0 = nh + j * 16 + quad * 4;
        const f32x4 b4 = *(const f32x4*)(bs + n0);
        const int cn = n0 >> 3, off = n0 & 7;
        #pragma unroll
        for (int i = 0; i < 4; ++i) {
            const int m = mh + i * 16 + s;
            u16x4 ov;
            #pragma unroll
            for (int r = 0; r < 4; ++r) ov[r] = f2bf(acc[j][i][r] + b4[r]);
            *(u16x4*)(Ct + m * 128 + ((cn ^ (m & 15)) * 8) + off) = ov;
        }
    }
    __syncthreads();
    {
        const int m = tid >> 1, half = tid & 1;
        u16* dst = OUT + (size_t)(bm + m) * D_ + bn + half * 64;
        #pragma unroll
        for (int cc = 0; cc < 8; ++cc) {
            const int cn = half * 8 + cc;
            u16x8 v = *(const u16x8*)(Ct + m * 128 + ((cn ^ (m & 15)) * 8));
            *(u16x8*)(dst + cc * 8) = v;
        }
    }
}

// ---------------------------------------------------------------------------
// Final GEMM: out = ob @ Wo^T + bo + x (fp32 out). dbuf + C^T + float4 stores.
// ---------------------------------------------------------------------------
__global__ __launch_bounds__(256) void gemm_final(
    const u16* __restrict__ A, const u16* __restrict__ W,
    const float* __restrict__ bias, const float* __restrict__ resid,
    float* __restrict__ outf)
{
    __shared__ __align__(16) u16 lds[16384];
    const int tid  = threadIdx.x;
    const int lane = tid & 63, w = tid >> 6;
    const int s    = lane & 15, quad = lane >> 4;
    const int bm   = blockIdx.y * 128, bn = blockIdx.x * 128;
    const int mh   = (w >> 1) * 64, nh = (w & 1) * 64;
    const int wb   = tid & ~63;
    const int cq   = quad ^ ((s >> 1) & 3);
    f32x4 acc[4][4];
    #pragma unroll
    for (int j = 0; j < 4; ++j)
        #pragma unroll
        for (int i = 0; i < 4; ++i) acc[j][i] = (f32x4){0.f, 0.f, 0.f, 0.f};

    {
        int c = tid, r = c >> 2, cs = (c & 3) ^ ((r >> 1) & 3);
        gld16(A + (size_t)(bm + r) * D_ + cs * 8, lds + (size_t)wb * 8);
        gld16(W + (size_t)(bn + r) * D_ + cs * 8, lds + 8192 + (size_t)wb * 8);
        c = tid + 256; r = c >> 2; cs = (c & 3) ^ ((r >> 1) & 3);
        gld16(A + (size_t)(bm + r) * D_ + cs * 8, lds + (size_t)(wb + 256) * 8);
        gld16(W + (size_t)(bn + r) * D_ + cs * 8, lds + 8192 + (size_t)(wb + 256) * 8);
    }
    __syncthreads();

    for (int t = 0; t < 24; ++t) {
        const u16* Ab = lds + (t & 1) * 4096;
        const u16* Bb = lds + 8192 + (t & 1) * 4096;
        if (t < 23) {
            const int k0 = (t + 1) * 32;
            u16* Ad = lds + ((t + 1) & 1) * 4096;
            u16* Bd = lds + 8192 + ((t + 1) & 1) * 4096;
            int c = tid, r = c >> 2, cs = (c & 3) ^ ((r >> 1) & 3);
            gld16(A + (size_t)(bm + r) * D_ + k0 + cs * 8, Ad + (size_t)wb * 8);
            gld16(W + (size_t)(bn + r) * D_ + k0 + cs * 8, Bd + (size_t)wb * 8);
            c = tid + 256; r = c >> 2; cs = (c & 3) ^ ((r >> 1) & 3);
            gld16(A + (size_t)(bm + r) * D_ + k0 + cs * 8, Ad + (size_t)(wb + 256) * 8);
            gld16(W + (size_t)(bn + r) * D_ + k0 + cs * 8, Bd + (size_t)(wb + 256) * 8);
        }
        bf16x8 af[4], bf[4];
        #pragma unroll
        for (int i = 0; i < 4; ++i)
            af[i] = *(const bf16x8*)(Ab + (mh + i * 16 + s) * 32 + cq * 8);
        #pragma unroll
        for (int j = 0; j < 4; ++j)
            bf[j] = *(const bf16x8*)(Bb + (nh + j * 16 + s) * 32 + cq * 8);
        #pragma unroll
        for (int j = 0; j < 4; ++j)
            #pragma unroll
            for (int i = 0; i < 4; ++i)
                acc[j][i] = __builtin_amdgcn_mfma_f32_16x16x32_bf16(
                    bf[j], af[i], acc[j][i], 0, 0, 0);
        __syncthreads();
    }
    #pragma unroll
    for (int j = 0; j < 4; ++j) {
        const int n0 = nh + j * 16 + quad * 4;
        const float4 b4 = *(const float4*)(bias + bn + n0);
        #pragma unroll
        for (int i = 0; i < 4; ++i) {
            const int m = mh + i * 16 + s;
            const size_t base = (size_t)(bm + m) * D_ + bn + n0;
            const float4 rs = *(const float4*)(resid + base);
            float4 o;
            o.x = acc[j][i][0] + b4.x + rs.x;
            o.y = acc[j][i][1] + b4.y + rs.y;
            o.z = acc[j][i][2] + b4.z + rs.z;
            o.w = acc[j][i][3] + b4.w + rs.w;
            *(float4*)(outf + base) = o;
        }
    }
}

// ---------------------------------------------------------------------------
// Row LayerNorm (pop var, eps 1e-5) * gamma * scale, bf16 in -> bf16 out.
// ---------------------------------------------------------------------------
__global__ __launch_bounds__(256) void ln_bf16(
    const u16* __restrict__ X, const float* __restrict__ gamma,
    u16* __restrict__ Y, float scale)
{
    const int row = blockIdx.x;
    const u16* x = X + (size_t)row * D_;
    const int tid = threadIdx.x;
    float v[3];
    float lsum = 0.f, lsq = 0.f;
    #pragma unroll
    for (int e = 0; e < 3; ++e) {
        float t = bf2f(x[tid + e * 256]);
        v[e] = t; lsum += t; lsq += t * t;
    }
    #pragma unroll
    for (int off = 32; off > 0; off >>= 1) {
        lsum += __shfl_down(lsum, off);
        lsq  += __shfl_down(lsq,  off);
    }
    __shared__ float s1[4], s2[4];
    const int wv = tid >> 6, lane = tid & 63;
    if (lane == 0) { s1[wv] = lsum; s2[wv] = lsq; }
    __syncthreads();
    const float sum = s1[0] + s1[1] + s1[2] + s1[3];
    const float sq  = s2[0] + s2[1] + s2[2] + s2[3];
    const float mu  = sum * (1.0f / D_);
    const float var = sq * (1.0f / D_) - mu * mu;
    const float inv = rsqrtf(var + 1e-5f) * scale;
    #pragma unroll
    for (int e = 0; e < 3; ++e) {
        int c = tid + e * 256;
        Y[(size_t)row * D_ + c] = f2bf((v[e] - mu) * inv * gamma[c]);
    }
}

// ---------------------------------------------------------------------------
// Pass A: per-key l = sum_q exp2(s~[q,k]) (NO max: QK-norm bounds scores).
// ---------------------------------------------------------------------------
__global__ __launch_bounds__(256) void attn_stats(
    const u16* __restrict__ Qb, const u16* __restrict__ Kb,
    float* __restrict__ Rl)
{
    __shared__ __align__(16) u16 Ks[128 * 64];       // 16 KB
    __shared__ __align__(16) u16 Qs[2][128 * 64];    // 32 KB dbuf
    __shared__ float lbuf[4][64];
    const int tid  = threadIdx.x;
    const int lane = tid & 63, w = tid >> 6;
    const int s    = lane & 15, quad = lane >> 4;
    const int s7   = s & 7;
    const int bh   = blockIdx.y;
    const int b    = bh / NH_, h = bh % NH_;
    const int kbase = blockIdx.x * 128;
    const u16* Qg = Qb + (size_t)b * L_ * D_ + h * HD_;
    const u16* Kg = Kb + (size_t)b * L_ * D_ + h * HD_;
    const int mh = (w >> 1) * 64;   // key half
    const int nh = (w & 1) * 64;    // query half
    const int wb = tid & ~63;

    #pragma unroll
    for (int c0 = 0; c0 < 1024; c0 += 256) {
        int c = c0 + tid, r = c >> 3, cc = (c & 7) ^ (r & 7);
        gld16(Kg + (size_t)(kbase + r) * D_ + cc * 8, Ks + (size_t)(c0 + wb) * 8);
        gld16(Qg + (size_t)r * D_ + cc * 8, Qs[0] + (size_t)(c0 + wb) * 8);
    }
    __syncthreads();
    bf16x8 kf[2][4];
    #pragma unroll
    for (int kk = 0; kk < 2; ++kk)
        #pragma unroll
        for (int i = 0; i < 4; ++i)
            kf[kk][i] = *(const bf16x8*)(Ks + (mh + i * 16 + s) * 64 +
                                         ((kk * 4 + quad) ^ s7) * 8);
    float lacc[4][4];
    #pragma unroll
    for (int i = 0; i < 4; ++i)
        #pragma unroll
        for (int r = 0; r < 4; ++r) lacc[i][r] = 0.f;

    for (int t = 0; t < 16; ++t) {
        if (t < 15) {
            const int qn = (t + 1) * 128;
            u16* Qd = Qs[(t + 1) & 1];
            #pragma unroll
            for (int c0 = 0; c0 < 1024; c0 += 256) {
                int c = c0 + tid, r = c >> 3, cc = (c & 7) ^ (r & 7);
                gld16(Qg + (size_t)(qn + r) * D_ + cc * 8, Qd + (size_t)(c0 + wb) * 8);
            }
        }
        const u16* Qt = Qs[t & 1];
        f32x4 acc[4][4];
        #pragma unroll
        for (int i = 0; i < 4; ++i)
            #pragma unroll
            for (int j = 0; j < 4; ++j) acc[i][j] = (f32x4){0.f, 0.f, 0.f, 0.f};
        #pragma unroll
        for (int kk = 0; kk < 2; ++kk) {
            bf16x8 bf[4];
            #pragma unroll
            for (int j = 0; j < 4; ++j)
                bf[j] = *(const bf16x8*)(Qt + (nh + j * 16 + s) * 64 +
                                         ((kk * 4 + quad) ^ s7) * 8);
            #pragma unroll
            for (int i = 0; i < 4; ++i)
                #pragma unroll
                for (int j = 0; j < 4; ++j)
                    acc[i][j] = __builtin_amdgcn_mfma_f32_16x16x32_bf16(
                        kf[kk][i], bf[j], acc[i][j], 0, 0, 0);
        }
        #pragma unroll
        for (int i = 0; i < 4; ++i)
            #pragma unroll
            for (int r = 0; r < 4; ++r) {
                float l0 = ex2(acc[i][0][r]) + ex2(acc[i][1][r]);
                float l1 = ex2(acc[i][2][r]) + ex2(acc[i][3][r]);
                lacc[i][r] += l0 + l1;
            }
        __syncthreads();
    }
    #pragma unroll
    for (int i = 0; i < 4; ++i)
        #pragma unroll
        for (int r = 0; r < 4; ++r) {
            float v = lacc[i][r];
            #pragma unroll
            for (int d2 = 1; d2 < 16; d2 <<= 1) v += __shfl_xor(v, d2);
            lacc[i][r] = v;
        }
    if (s == 0) {
        #pragma unroll
        for (int i = 0; i < 4; ++i)
            #pragma unroll
            for (int r = 0; r < 4; ++r)
                lbuf[w][i * 16 + quad * 4 + r] = lacc[i][r];
    }
    __syncthreads();
    if (tid < 128) {
        int kh = tid >> 6, kl = tid & 63;
        float l = lbuf[kh * 2][kl] + lbuf[kh * 2 + 1][kl];
        Rl[(size_t)bh * L_ + kbase + tid] = 1.0f / l;
    }
}

// ---------------------------------------------------------------------------
// V transpose + fold 1/l + PV key-permutation (p = ((a>>2)&3)*8+((a>>4)&1)*4+(a&3))
// ---------------------------------------------------------------------------
__global__ __launch_bounds__(256) void transpose_v_scaled(
    const u16* __restrict__ Vb, const float* __restrict__ Rl,
    u16* __restrict__ Vt)
{
    const int l0 = blockIdx.x * 64, h = blockIdx.y, b = blockIdx.z;
    const int bh = b * NH_ + h;
    __shared__ __align__(16) u16 Ts[64][72];
    const int tid = threadIdx.x;
    #pragma unroll
    for (int c = tid; c < 512; c += 256) {
        int r = c >> 3, cc = c & 7;
        u16x8 val = *(const u16x8*)(Vb + (size_t)(b * L_ + l0 + r) * D_ + h * HD_ + cc * 8);
        const float rl = Rl[(size_t)bh * L_ + l0 + r];
        #pragma unroll
        for (int e = 0; e < 8; ++e) val[e] = f2bf(bf2f(val[e]) * rl);
        *(u16x8*)(&Ts[r][cc * 8]) = val;
    }
    __syncthreads();
    const int d = tid >> 2, lc = (tid & 3) * 16;
    u16 tmp[16];
    #pragma unroll
    for (int e = 0; e < 16; ++e) tmp[e] = Ts[lc + e][d];
    u16* dst = Vt + ((size_t)bh * HD_ + d) * L_ + l0 + (lc & 32) + ((lc >> 4) & 1) * 4;
    #pragma unroll
    for (int qd = 0; qd < 4; ++qd) {
        u16x4 o;
        #pragma unroll
        for (int e = 0; e < 4; ++e) o[e] = tmp[qd * 4 + e];
        *(u16x4*)(dst + qd * 8) = o;
    }
}

// ---------------------------------------------------------------------------
// Pass B: O^T = V'^T · P^T, P = exp2(s~) in registers. 128 q/block,
// wave = 64 keys x 32-q slice. 48 KB LDS -> 3 blocks/CU.
// ---------------------------------------------------------------------------
__global__ __launch_bounds__(256, 3) void attn_out(
    const u16* __restrict__ Qb, const u16* __restrict__ Kb,
    const u16* __restrict__ Vt, u16* __restrict__ Ob)
{
    __shared__ __align__(16) u16 Qs[128 * 64];     // 16 KB: Q staging -> O epilogue
    __shared__ __align__(16) u16 Ks[2][64 * 64];   // 16 KB dbuf
    __shared__ __align__(16) u16 Vts[2][64 * 64];  // 16 KB dbuf
    const int tid  = threadIdx.x;
    const int lane = tid & 63, w = tid >> 6;
    const int s    = lane & 15, quad = lane >> 4;
    const int s7   = s & 7;
    const int bh   = blockIdx.y;
    const int b    = bh / NH_, h = bh % NH_;
    const int qbase = blockIdx.x * 128;
    const int qw   = w * 32;                        // this wave's 32-q slice
    const u16* Qg = Qb + (size_t)b * L_ * D_ + h * HD_;
    const u16* Kg = Kb + (size_t)b * L_ * D_ + h * HD_;
    const u16* Vg = Vt + (size_t)bh * HD_ * L_;
    const int wb = tid & ~63;

    // stage Q (1024 chunks, 4/thread) + preload K/V tile 0
    #pragma unroll
    for (int c0 = 0; c0 < 1024; c0 += 256) {
        int c = c0 + tid, r = c >> 3, cc = (c & 7) ^ (r & 7);
        gld16(Qg + (size_t)(qbase + r) * D_ + cc * 8, Qs + (size_t)(c0 + wb) * 8);
    }
    {
        int c = tid, r = c >> 3, cc = (c & 7) ^ (r & 7);
        gld16(Kg + (size_t)r * D_ + cc * 8, Ks[0] + (size_t)wb * 8);
        gld16(Vg + (size_t)r * L_ + cc * 8, Vts[0] + (size_t)wb * 8);
        c = tid + 256; r = c >> 3; cc = (c & 7) ^ (r & 7);
        gld16(Kg + (size_t)r * D_ + cc * 8, Ks[0] + (size_t)(wb + 256) * 8);
        gld16(Vg + (size_t)r * L_ + cc * 8, Vts[0] + (size_t)(wb + 256) * 8);
    }
    __syncthreads();
    // hoist Q B-frags (loop-invariant), j over 2 q-tiles of 16
    bf16x8 qf[2][2];
    #pragma unroll
    for (int kk = 0; kk < 2; ++kk)
        #pragma unroll
        for (int j = 0; j < 2; ++j)
            qf[kk][j] = *(const bf16x8*)(Qs + (qw + j * 16 + s) * 64 +
                                         ((kk * 4 + quad) ^ s7) * 8);
    f32x4 acc_o[4][2];
    #pragma unroll
    for (int i = 0; i < 4; ++i)
        #pragma unroll
        for (int j = 0; j < 2; ++j) acc_o[i][j] = (f32x4){0.f, 0.f, 0.f, 0.f};

    for (int t = 0; t < 32; ++t) {
        const u16* Kt  = Ks[t & 1];
        const u16* Vtt = Vts[t & 1];
        if (t < 31) {
            const int kn = (t + 1) * 64;
            u16* Kd = Ks[(t + 1) & 1];
            u16* Vd = Vts[(t + 1) & 1];
            int c = tid, r = c >> 3, cc = (c & 7) ^ (r & 7);
            gld16(Kg + (size_t)(kn + r) * D_ + cc * 8, Kd + (size_t)wb * 8);
            gld16(Vg + (size_t)r * L_ + kn + cc * 8,   Vd + (size_t)wb * 8);
            c = tid + 256; r = c >> 3; cc = (c & 7) ^ (r & 7);
            gld16(Kg + (size_t)(kn + r) * D_ + cc * 8, Kd + (size_t)(wb + 256) * 8);
            gld16(Vg + (size_t)r * L_ + kn + cc * 8,   Vd + (size_t)(wb + 256) * 8);
        }
        // ---- S: 64 keys x 32 queries (this wave's slice) ----
        f32x4 acc_s[4][2];
        #pragma unroll
        for (int i = 0; i < 4; ++i)
            #pragma unroll
            for (int j = 0; j < 2; ++j) acc_s[i][j] = (f32x4){0.f, 0.f, 0.f, 0.f};
        #pragma unroll
        for (int kk = 0; kk < 2; ++kk) {
            bf16x8 kfr[4];
            #pragma unroll
            for (int i = 0; i < 4; ++i)
                kfr[i] = *(const bf16x8*)(Kt + (i * 16 + s) * 64 +
                                          ((kk * 4 + quad) ^ s7) * 8);
            #pragma unroll
            for (int i = 0; i < 4; ++i)
                #pragma unroll
                for (int j = 0; j < 2; ++j)
                    acc_s[i][j] = __builtin_amdgcn_mfma_f32_16x16x32_bf16(
                        kfr[i], qf[kk][j], acc_s[i][j], 0, 0, 0);
        }
        // ---- P = exp2(s~), packed bf16 pairs (register only) ----
        unsigned pk[4][2][2];
        #pragma unroll
        for (int i = 0; i < 4; ++i)
            #pragma unroll
            for (int j = 0; j < 2; ++j) {
                float p0 = ex2(acc_s[i][j][0]), p1 = ex2(acc_s[i][j][1]);
                float p2 = ex2(acc_s[i][j][2]), p3 = ex2(acc_s[i][j][3]);
                pk[i][j][0] = packbf(p0, p1);
                pk[i][j][1] = packbf(p2, p3);
            }
        // ---- O^T += V'^T · P^T (B-frags = register renames of pk) ----
        #pragma unroll
        for (int kk = 0; kk < 2; ++kk) {
            bf16x8 av[4];
            #pragma unroll
            for (int i = 0; i < 4; ++i)
                av[i] = *(const bf16x8*)(Vtt + (i * 16 + s) * 64 +
                                         ((kk * 4 + quad) ^ s7) * 8);
            #pragma unroll
            for (int j = 0; j < 2; ++j) {
                union { unsigned u[4]; bf16x8 v; } bu;
                bu.u[0] = pk[2 * kk][j][0];
                bu.u[1] = pk[2 * kk][j][1];
                bu.u[2] = pk[2 * kk + 1][j][0];
                bu.u[3] = pk[2 * kk + 1][j][1];
                #pragma unroll
                for (int i = 0; i < 4; ++i)
                    acc_o[i][j] = __builtin_amdgcn_mfma_f32_16x16x32_bf16(
                        av[i], bu.v, acc_o[i][j], 0, 0, 0);
            }
        }
        __syncthreads();
    }
    // ---- epilogue: O^T -> Qs as [128 q][64 d] (swizzled) -> coalesced store
    #pragma unroll
    for (int i = 0; i < 4; ++i) {
        const int dchunk = i * 2 + (quad >> 1), doff = (quad & 1) * 4;
        #pragma unroll
        for (int j = 0; j < 2; ++j) {
            const int q = qw + j * 16 + s;
            u16x4 ov;
            #pragma unroll
            for (int r = 0; r < 4; ++r) ov[r] = f2bf(acc_o[i][j][r]);
            *(u16x4*)(Qs + q * 64 + (dchunk ^ s7) * 8 + doff) = ov;
        }
    }
    __syncthreads();
    {
        const int q = tid >> 1, half = tid & 1, q7 = q & 7;
        u16* dst = Ob + (size_t)(b * L_ + qbase + q) * D_ + h * HD_ + half * 32;
        #pragma unroll
        for (int c = 0; c < 4; ++c) {
            const int cn = half * 4 + c;
            u16x8 v = *(const u16x8*)(Qs + q * 64 + ((cn ^ q7) * 8));
            *(u16x8*)(dst + c * 8) = v;
        }
    }
}

// ---------------------------------------------------------------------------
extern "C" void kernel_launch(void* const* d_in, const int* in_sizes, int n_in,
                              void* d_out, int out_size, void* d_ws, size_t ws_size,
                              hipStream_t stream)
{
    const float* x  = (const float*)d_in[0];
    const float* Wq = (const float*)d_in[1];
    const float* Wk = (const float*)d_in[2];
    const float* bk = (const float*)d_in[3];
    const float* Wv = (const float*)d_in[4];
    const float* bv = (const float*)d_in[5];
    const float* gq = (const float*)d_in[6];
    const float* gk = (const float*)d_in[7];
    const float* Wo = (const float*)d_in[8];
    const float* bo = (const float*)d_in[9];
    float* out = (float*)d_out;

    char* p = (char*)d_ws;
    u16* xb   = (u16*)p;  p += (size_t)M_ * D_ * 2;
    u16* qpre = (u16*)p;  p += (size_t)M_ * D_ * 2;   // ob aliases after LN
    u16* kpre = (u16*)p;  p += (size_t)M_ * D_ * 2;   // vt aliases after LN
    u16* vb   = (u16*)p;  p += (size_t)M_ * D_ * 2;
    u16* qb   = (u16*)p;  p += (size_t)M_ * D_ * 2;
    u16* kb   = (u16*)p;  p += (size_t)M_ * D_ * 2;
    u16* wqb  = (u16*)p;  p += (size_t)D_ * D_ * 2;
    u16* wkb  = (u16*)p;  p += (size_t)D_ * D_ * 2;
    u16* wvb  = (u16*)p;  p += (size_t)D_ * D_ * 2;
    u16* wob  = (u16*)p;  p += (size_t)D_ * D_ * 2;
    float* Rl = (float*)p; p += (size_t)B_ * NH_ * L_ * 4;
    u16* ob = qpre;   // dead after LN
    u16* vt = kpre;   // dead after LN

    const int nX = M_ * D_, nW = D_ * D_;
    cvt_bf16_kernel<<<nX / 2048, 256, 0, stream>>>(x, xb, nX / 8);
    cvt4_bf16_kernel<<<dim3(nW / 2048, 4), 256, 0, stream>>>(
        Wq, Wk, Wv, Wo, wqb, wkb, wvb, wob, nW / 8);

    gemm_qkv<<<dim3(18, M_ / 128), 256, 0, stream>>>(
        xb, wqb, wkb, wvb, bk, bv, qpre, kpre, vb);

    ln_bf16<<<M_, 256, 0, stream>>>(qpre, gq, qb, SC2);
    ln_bf16<<<M_, 256, 0, stream>>>(kpre, gk, kb, 1.0f);

    dim3 sgrid(L_ / 128, B_ * NH_);   // (16, 48)
    attn_stats<<<sgrid, 256, 0, stream>>>(qb, kb, Rl);
    transpose_v_scaled<<<dim3(L_ / 64, NH_, B_), 256, 0, stream>>>(vb, Rl, vt);
    dim3 ogrid(L_ / 128, B_ * NH_);   // (16, 48)
    attn_out<<<ogrid, 256, 0, stream>>>(qb, kb, vt, ob);

    gemm_final<<<dim3(D_ / 128, M_ / 128), 256, 0, stream>>>(ob, wob, bo, x, out);
}

// Round 8
// 290.455 us; speedup vs baseline: 1.1217x; 1.0630x over previous
//
#include <hip/hip_runtime.h>
#include <cstddef>
#include <cstdint>

// ---------------------------------------------------------------------------
// MultiheadSelfAttn (b=4, l=2048, d=768, nh=12, hd=64), softmax over QUERY axis.
// cvt -> fused QKV GEMM (dbuf, C^T, bf16 LDS-coalesced epilogue) ->
// LN(bf16 in -> bf16 out, SC2 folded into q) -> stats (no-max exp2 sum) ->
// V transpose (*1/l, PV key-permuted) -> attention out (register-P) ->
// final GEMM (dbuf, C^T, float4 epilogue).
// XCD-aware 1-D grid swizzle on all 4 heavy kernels: blocks sharing a
// streamed operand land on the same XCD (i%8) -> per-XCD L2-resident staging.
// ---------------------------------------------------------------------------

typedef unsigned short u16;
typedef short  bf16x8 __attribute__((ext_vector_type(8)));   // MFMA A/B frag
typedef float  f32x4  __attribute__((ext_vector_type(4)));   // MFMA C/D frag
typedef unsigned short u16x8 __attribute__((ext_vector_type(8)));
typedef unsigned short u16x4 __attribute__((ext_vector_type(4)));

#define B_   4
#define L_   2048
#define D_   768
#define NH_  12
#define HD_  64
#define M_   (B_*L_)
#define SC2  (0.125f * 1.44269504088896f)   // scale * log2(e), folded into qb

__device__ __forceinline__ float ex2(float x) { return __builtin_amdgcn_exp2f(x); }

__device__ __forceinline__ u16 f2bf(float f) {            // RNE
    union { float f; unsigned u; } v; v.f = f;
    unsigned r = v.u + 0x7FFFu + ((v.u >> 16) & 1u);
    return (u16)(r >> 16);
}
__device__ __forceinline__ float bf2f(u16 b) {
    union { unsigned u; float f; } v; v.u = ((unsigned)b) << 16;
    return v.f;
}
__device__ __forceinline__ unsigned fbits(float f) {
    union { float f; unsigned u; } v; v.f = f; return v.u;
}
// pack two f32 -> (bf16(lo) | bf16(hi)<<16), truncation (P>=0, slack ok)
__device__ __forceinline__ unsigned packbf(float lo, float hi) {
    return __builtin_amdgcn_perm(fbits(hi), fbits(lo), 0x07060302u);
}

// async global->LDS, 16B/lane; LDS dest = wave-uniform base + lane*16.
__device__ __forceinline__ void gld16(const void* g, void* l) {
    __builtin_amdgcn_global_load_lds(
        (const __attribute__((address_space(1))) unsigned*)g,
        (__attribute__((address_space(3))) unsigned*)l, 16, 0, 0);
}

// ---------------------------------------------------------------------------
// fp32 -> bf16 bulk convert
// ---------------------------------------------------------------------------
__global__ __launch_bounds__(256) void cvt_bf16_kernel(
    const float* __restrict__ X, u16* __restrict__ Y, int n8)
{
    int i = blockIdx.x * 256 + threadIdx.x;
    if (i >= n8) return;
    const float4* xp = (const float4*)X + (size_t)i * 2;
    float4 a = xp[0], b = xp[1];
    u16x8 o;
    o[0] = f2bf(a.x); o[1] = f2bf(a.y); o[2] = f2bf(a.z); o[3] = f2bf(a.w);
    o[4] = f2bf(b.x); o[5] = f2bf(b.y); o[6] = f2bf(b.z); o[7] = f2bf(b.w);
    *((u16x8*)Y + i) = o;
}

__global__ __launch_bounds__(256) void cvt4_bf16_kernel(
    const float* __restrict__ W0, const float* __restrict__ W1,
    const float* __restrict__ W2, const float* __restrict__ W3,
    u16* __restrict__ Y0, u16* __restrict__ Y1,
    u16* __restrict__ Y2, u16* __restrict__ Y3, int n8)
{
    const float* X; u16* Y;
    switch (blockIdx.y) {
        case 0: X = W0; Y = Y0; break;
        case 1: X = W1; Y = Y1; break;
        case 2: X = W2; Y = Y2; break;
        default: X = W3; Y = Y3; break;
    }
    int i = blockIdx.x * 256 + threadIdx.x;
    if (i >= n8) return;
    const float4* xp = (const float4*)X + (size_t)i * 2;
    float4 a = xp[0], b = xp[1];
    u16x8 o;
    o[0] = f2bf(a.x); o[1] = f2bf(a.y); o[2] = f2bf(a.z); o[3] = f2bf(a.w);
    o[4] = f2bf(b.x); o[5] = f2bf(b.y); o[6] = f2bf(b.z); o[7] = f2bf(b.w);
    *((u16x8*)Y + i) = o;
}

// ---------------------------------------------------------------------------
// Fused QKV GEMM: A[8192,768] x {Wq,Wk,Wv}^T -> bf16. 128x128 tile, BK=32,
// dbuf (1 barrier/iter), BK-swizzled LDS, C^T accumulate, bf16 LDS epilogue.
// 1-D grid 1152 = 8 XCD x (8 bm x 18 seg/bn): same-bm blocks share one XCD.
// ---------------------------------------------------------------------------
__global__ __launch_bounds__(256) void gemm_qkv(
    const u16* __restrict__ A,
    const u16* __restrict__ W0, const u16* __restrict__ W1,
    const u16* __restrict__ W2,
    const float* __restrict__ bk, const float* __restrict__ bv,
    u16* __restrict__ q_o, u16* __restrict__ k_o, u16* __restrict__ v_o)
{
    __shared__ __align__(16) u16 lds[16384];   // [A0|A1|B0|B1] 4x8KB -> Ct 32KB
    __shared__ float bs[128];
    const int tid  = threadIdx.x;
    const int lane = tid & 63, w = tid >> 6;
    const int s    = lane & 15, quad = lane >> 4;
    // XCD swizzle: i%8 = XCD; 18 consecutive j share bm (A-tile L2-resident)
    const int bid  = blockIdx.x;
    const int xcd  = bid & 7, j0 = bid >> 3;       // j0 in 0..143
    const int bm   = (xcd * 8 + j0 / 18) * 128;
    const int sub  = j0 % 18;
    const int seg  = sub / 6;
    const int bn   = (sub % 6) * 128;
    const u16* W = (seg == 0) ? W0 : ((seg == 1) ? W1 : W2);
    u16* OUT = (seg == 0) ? q_o : ((seg == 1) ? k_o : v_o);
    const int mh = (w >> 1) * 64, nh = (w & 1) * 64;
    const int wb = tid & ~63;
    const int cq = quad ^ ((s >> 1) & 3);      // swizzled frag chunk

    if (tid < 128)
        bs[tid] = (seg == 1) ? bk[bn + tid] : ((seg == 2) ? bv[bn + tid] : 0.0f);

    f32x4 acc[4][4];   // [j (n-tile)][i (m-tile)], C^T
    #pragma unroll
    for (int j = 0; j < 4; ++j)
        #pragma unroll
        for (int i = 0; i < 4; ++i) acc[j][i] = (f32x4){0.f, 0.f, 0.f, 0.f};

    {
        int c = tid, r = c >> 2, cs = (c & 3) ^ ((r >> 1) & 3);
        gld16(A + (size_t)(bm + r) * D_ + cs * 8, lds + (size_t)wb * 8);
        gld16(W + (size_t)(bn + r) * D_ + cs * 8, lds + 8192 + (size_t)wb * 8);
        c = tid + 256; r = c >> 2; cs = (c & 3) ^ ((r >> 1) & 3);
        gld16(A + (size_t)(bm + r) * D_ + cs * 8, lds + (size_t)(wb + 256) * 8);
        gld16(W + (size_t)(bn + r) * D_ + cs * 8, lds + 8192 + (size_t)(wb + 256) * 8);
    }
    __syncthreads();

    for (int t = 0; t < 24; ++t) {
        const u16* Ab = lds + (t & 1) * 4096;
        const u16* Bb = lds + 8192 + (t & 1) * 4096;
        if (t < 23) {
            const int k0 = (t + 1) * 32;
            u16* Ad = lds + ((t + 1) & 1) * 4096;
            u16* Bd = lds + 8192 + ((t + 1) & 1) * 4096;
            int c = tid, r = c >> 2, cs = (c & 3) ^ ((r >> 1) & 3);
            gld16(A + (size_t)(bm + r) * D_ + k0 + cs * 8, Ad + (size_t)wb * 8);
            gld16(W + (size_t)(bn + r) * D_ + k0 + cs * 8, Bd + (size_t)wb * 8);
            c = tid + 256; r = c >> 2; cs = (c & 3) ^ ((r >> 1) & 3);
            gld16(A + (size_t)(bm + r) * D_ + k0 + cs * 8, Ad + (size_t)(wb + 256) * 8);
            gld16(W + (size_t)(bn + r) * D_ + k0 + cs * 8, Bd + (size_t)(wb + 256) * 8);
        }
        bf16x8 af[4], bf[4];
        #pragma unroll
        for (int i = 0; i < 4; ++i)
            af[i] = *(const bf16x8*)(Ab + (mh + i * 16 + s) * 32 + cq * 8);
        #pragma unroll
        for (int j = 0; j < 4; ++j)
            bf[j] = *(const bf16x8*)(Bb + (nh + j * 16 + s) * 32 + cq * 8);
        #pragma unroll
        for (int j = 0; j < 4; ++j)
            #pragma unroll
            for (int i = 0; i < 4; ++i)
                acc[j][i] = __builtin_amdgcn_mfma_f32_16x16x32_bf16(
                    bf[j], af[i], acc[j][i], 0, 0, 0);   // C^T: rows=n, cols=m
        __syncthreads();
    }
    // epilogue: bf16 + bias -> Ct[m][128] (chunk ^ (m&15)) -> coalesced store
    u16* Ct = lds;
    #pragma unroll
    for (int j = 0; j < 4; ++j) {
        const int n0 = nh + j * 16 + quad * 4;
        const f32x4 b4 = *(const f32x4*)(bs + n0);
        const int cn = n0 >> 3, off = n0 & 7;
        #pragma unroll
        for (int i = 0; i < 4; ++i) {
            const int m = mh + i * 16 + s;
            u16x4 ov;
            #pragma unroll
            for (int r = 0; r < 4; ++r) ov[r] = f2bf(acc[j][i][r] + b4[r]);
            *(u16x4*)(Ct + m * 128 + ((cn ^ (m & 15)) * 8) + off) = ov;
        }
    }
    __syncthreads();
    {
        const int m = tid >> 1, half = tid & 1;
        u16* dst = OUT + (size_t)(bm + m) * D_ + bn + half * 64;
        #pragma unroll
        for (int cc = 0; cc < 8; ++cc) {
            const int cn = half * 8 + cc;
            u16x8 v = *(const u16x8*)(Ct + m * 128 + ((cn ^ (m & 15)) * 8));
            *(u16x8*)(dst + cc * 8) = v;
        }
    }
}

// ---------------------------------------------------------------------------
// Final GEMM: out = ob @ Wo^T + bo + x (fp32 out). dbuf + C^T + float4 stores.
// 1-D grid 384 = 8 XCD x (8 bm x 6 bn).
// ---------------------------------------------------------------------------
__global__ __launch_bounds__(256) void gemm_final(
    const u16* __restrict__ A, const u16* __restrict__ W,
    const float* __restrict__ bias, const float* __restrict__ resid,
    float* __restrict__ outf)
{
    __shared__ __align__(16) u16 lds[16384];
    const int tid  = threadIdx.x;
    const int lane = tid & 63, w = tid >> 6;
    const int s    = lane & 15, quad = lane >> 4;
    const int bid  = blockIdx.x;
    const int xcd  = bid & 7, j0 = bid >> 3;       // j0 in 0..47
    const int bm   = (xcd * 8 + j0 / 6) * 128;
    const int bn   = (j0 % 6) * 128;
    const int mh   = (w >> 1) * 64, nh = (w & 1) * 64;
    const int wb   = tid & ~63;
    const int cq   = quad ^ ((s >> 1) & 3);
    f32x4 acc[4][4];
    #pragma unroll
    for (int j = 0; j < 4; ++j)
        #pragma unroll
        for (int i = 0; i < 4; ++i) acc[j][i] = (f32x4){0.f, 0.f, 0.f, 0.f};

    {
        int c = tid, r = c >> 2, cs = (c & 3) ^ ((r >> 1) & 3);
        gld16(A + (size_t)(bm + r) * D_ + cs * 8, lds + (size_t)wb * 8);
        gld16(W + (size_t)(bn + r) * D_ + cs * 8, lds + 8192 + (size_t)wb * 8);
        c = tid + 256; r = c >> 2; cs = (c & 3) ^ ((r >> 1) & 3);
        gld16(A + (size_t)(bm + r) * D_ + cs * 8, lds + (size_t)(wb + 256) * 8);
        gld16(W + (size_t)(bn + r) * D_ + cs * 8, lds + 8192 + (size_t)(wb + 256) * 8);
    }
    __syncthreads();

    for (int t = 0; t < 24; ++t) {
        const u16* Ab = lds + (t & 1) * 4096;
        const u16* Bb = lds + 8192 + (t & 1) * 4096;
        if (t < 23) {
            const int k0 = (t + 1) * 32;
            u16* Ad = lds + ((t + 1) & 1) * 4096;
            u16* Bd = lds + 8192 + ((t + 1) & 1) * 4096;
            int c = tid, r = c >> 2, cs = (c & 3) ^ ((r >> 1) & 3);
            gld16(A + (size_t)(bm + r) * D_ + k0 + cs * 8, Ad + (size_t)wb * 8);
            gld16(W + (size_t)(bn + r) * D_ + k0 + cs * 8, Bd + (size_t)wb * 8);
            c = tid + 256; r = c >> 2; cs = (c & 3) ^ ((r >> 1) & 3);
            gld16(A + (size_t)(bm + r) * D_ + k0 + cs * 8, Ad + (size_t)(wb + 256) * 8);
            gld16(W + (size_t)(bn + r) * D_ + k0 + cs * 8, Bd + (size_t)(wb + 256) * 8);
        }
        bf16x8 af[4], bf[4];
        #pragma unroll
        for (int i = 0; i < 4; ++i)
            af[i] = *(const bf16x8*)(Ab + (mh + i * 16 + s) * 32 + cq * 8);
        #pragma unroll
        for (int j = 0; j < 4; ++j)
            bf[j] = *(const bf16x8*)(Bb + (nh + j * 16 + s) * 32 + cq * 8);
        #pragma unroll
        for (int j = 0; j < 4; ++j)
            #pragma unroll
            for (int i = 0; i < 4; ++i)
                acc[j][i] = __builtin_amdgcn_mfma_f32_16x16x32_bf16(
                    bf[j], af[i], acc[j][i], 0, 0, 0);
        __syncthreads();
    }
    #pragma unroll
    for (int j = 0; j < 4; ++j) {
        const int n0 = nh + j * 16 + quad * 4;
        const float4 b4 = *(const float4*)(bias + bn + n0);
        #pragma unroll
        for (int i = 0; i < 4; ++i) {
            const int m = mh + i * 16 + s;
            const size_t base = (size_t)(bm + m) * D_ + bn + n0;
            const float4 rs = *(const float4*)(resid + base);
            float4 o;
            o.x = acc[j][i][0] + b4.x + rs.x;
            o.y = acc[j][i][1] + b4.y + rs.y;
            o.z = acc[j][i][2] + b4.z + rs.z;
            o.w = acc[j][i][3] + b4.w + rs.w;
            *(float4*)(outf + base) = o;
        }
    }
}

// ---------------------------------------------------------------------------
// Row LayerNorm (pop var, eps 1e-5) * gamma * scale, bf16 in -> bf16 out.
// ---------------------------------------------------------------------------
__global__ __launch_bounds__(256) void ln_bf16(
    const u16* __restrict__ X, const float* __restrict__ gamma,
    u16* __restrict__ Y, float scale)
{
    const int row = blockIdx.x;
    const u16* x = X + (size_t)row * D_;
    const int tid = threadIdx.x;
    float v[3];
    float lsum = 0.f, lsq = 0.f;
    #pragma unroll
    for (int e = 0; e < 3; ++e) {
        float t = bf2f(x[tid + e * 256]);
        v[e] = t; lsum += t; lsq += t * t;
    }
    #pragma unroll
    for (int off = 32; off > 0; off >>= 1) {
        lsum += __shfl_down(lsum, off);
        lsq  += __shfl_down(lsq,  off);
    }
    __shared__ float s1[4], s2[4];
    const int wv = tid >> 6, lane = tid & 63;
    if (lane == 0) { s1[wv] = lsum; s2[wv] = lsq; }
    __syncthreads();
    const float sum = s1[0] + s1[1] + s1[2] + s1[3];
    const float sq  = s2[0] + s2[1] + s2[2] + s2[3];
    const float mu  = sum * (1.0f / D_);
    const float var = sq * (1.0f / D_) - mu * mu;
    const float inv = rsqrtf(var + 1e-5f) * scale;
    #pragma unroll
    for (int e = 0; e < 3; ++e) {
        int c = tid + e * 256;
        Y[(size_t)row * D_ + c] = f2bf((v[e] - mu) * inv * gamma[c]);
    }
}

// ---------------------------------------------------------------------------
// Pass A: per-key l = sum_q exp2(s~[q,k]) (NO max: QK-norm bounds scores).
// 1-D grid 768 = 8 XCD x (6 bh x 16 k-blocks): same-bh blocks share one XCD.
// ---------------------------------------------------------------------------
__global__ __launch_bounds__(256) void attn_stats(
    const u16* __restrict__ Qb, const u16* __restrict__ Kb,
    float* __restrict__ Rl)
{
    __shared__ __align__(16) u16 Ks[128 * 64];       // 16 KB
    __shared__ __align__(16) u16 Qs[2][128 * 64];    // 32 KB dbuf
    __shared__ float lbuf[4][64];
    const int tid  = threadIdx.x;
    const int lane = tid & 63, w = tid >> 6;
    const int s    = lane & 15, quad = lane >> 4;
    const int s7   = s & 7;
    const int bid  = blockIdx.x;
    const int xcd  = bid & 7, j0 = bid >> 3;       // j0 in 0..95
    const int bh   = xcd * 6 + j0 / 16;
    const int kbase = (j0 % 16) * 128;
    const int b    = bh / NH_, h = bh % NH_;
    const u16* Qg = Qb + (size_t)b * L_ * D_ + h * HD_;
    const u16* Kg = Kb + (size_t)b * L_ * D_ + h * HD_;
    const int mh = (w >> 1) * 64;   // key half
    const int nh = (w & 1) * 64;    // query half
    const int wb = tid & ~63;

    #pragma unroll
    for (int c0 = 0; c0 < 1024; c0 += 256) {
        int c = c0 + tid, r = c >> 3, cc = (c & 7) ^ (r & 7);
        gld16(Kg + (size_t)(kbase + r) * D_ + cc * 8, Ks + (size_t)(c0 + wb) * 8);
        gld16(Qg + (size_t)r * D_ + cc * 8, Qs[0] + (size_t)(c0 + wb) * 8);
    }
    __syncthreads();
    bf16x8 kf[2][4];
    #pragma unroll
    for (int kk = 0; kk < 2; ++kk)
        #pragma unroll
        for (int i = 0; i < 4; ++i)
            kf[kk][i] = *(const bf16x8*)(Ks + (mh + i * 16 + s) * 64 +
                                         ((kk * 4 + quad) ^ s7) * 8);
    float lacc[4][4];
    #pragma unroll
    for (int i = 0; i < 4; ++i)
        #pragma unroll
        for (int r = 0; r < 4; ++r) lacc[i][r] = 0.f;

    for (int t = 0; t < 16; ++t) {
        if (t < 15) {
            const int qn = (t + 1) * 128;
            u16* Qd = Qs[(t + 1) & 1];
            #pragma unroll
            for (int c0 = 0; c0 < 1024; c0 += 256) {
                int c = c0 + tid, r = c >> 3, cc = (c & 7) ^ (r & 7);
                gld16(Qg + (size_t)(qn + r) * D_ + cc * 8, Qd + (size_t)(c0 + wb) * 8);
            }
        }
        const u16* Qt = Qs[t & 1];
        f32x4 acc[4][4];
        #pragma unroll
        for (int i = 0; i < 4; ++i)
            #pragma unroll
            for (int j = 0; j < 4; ++j) acc[i][j] = (f32x4){0.f, 0.f, 0.f, 0.f};
        #pragma unroll
        for (int kk = 0; kk < 2; ++kk) {
            bf16x8 bf[4];
            #pragma unroll
            for (int j = 0; j < 4; ++j)
                bf[j] = *(const bf16x8*)(Qt + (nh + j * 16 + s) * 64 +
                                         ((kk * 4 + quad) ^ s7) * 8);
            #pragma unroll
            for (int i = 0; i < 4; ++i)
                #pragma unroll
                for (int j = 0; j < 4; ++j)
                    acc[i][j] = __builtin_amdgcn_mfma_f32_16x16x32_bf16(
                        kf[kk][i], bf[j], acc[i][j], 0, 0, 0);
        }
        #pragma unroll
        for (int i = 0; i < 4; ++i)
            #pragma unroll
            for (int r = 0; r < 4; ++r) {
                float l0 = ex2(acc[i][0][r]) + ex2(acc[i][1][r]);
                float l1 = ex2(acc[i][2][r]) + ex2(acc[i][3][r]);
                lacc[i][r] += l0 + l1;
            }
        __syncthreads();
    }
    #pragma unroll
    for (int i = 0; i < 4; ++i)
        #pragma unroll
        for (int r = 0; r < 4; ++r) {
            float v = lacc[i][r];
            #pragma unroll
            for (int d2 = 1; d2 < 16; d2 <<= 1) v += __shfl_xor(v, d2);
            lacc[i][r] = v;
        }
    if (s == 0) {
        #pragma unroll
        for (int i = 0; i < 4; ++i)
            #pragma unroll
            for (int r = 0; r < 4; ++r)
                lbuf[w][i * 16 + quad * 4 + r] = lacc[i][r];
    }
    __syncthreads();
    if (tid < 128) {
        int kh = tid >> 6, kl = tid & 63;
        float l = lbuf[kh * 2][kl] + lbuf[kh * 2 + 1][kl];
        Rl[(size_t)bh * L_ + kbase + tid] = 1.0f / l;
    }
}

// ---------------------------------------------------------------------------
// V transpose + fold 1/l + PV key-permutation (p = ((a>>2)&3)*8+((a>>4)&1)*4+(a&3))
// ---------------------------------------------------------------------------
__global__ __launch_bounds__(256) void transpose_v_scaled(
    const u16* __restrict__ Vb, const float* __restrict__ Rl,
    u16* __restrict__ Vt)
{
    const int l0 = blockIdx.x * 64, h = blockIdx.y, b = blockIdx.z;
    const int bh = b * NH_ + h;
    __shared__ __align__(16) u16 Ts[64][72];
    const int tid = threadIdx.x;
    #pragma unroll
    for (int c = tid; c < 512; c += 256) {
        int r = c >> 3, cc = c & 7;
        u16x8 val = *(const u16x8*)(Vb + (size_t)(b * L_ + l0 + r) * D_ + h * HD_ + cc * 8);
        const float rl = Rl[(size_t)bh * L_ + l0 + r];
        #pragma unroll
        for (int e = 0; e < 8; ++e) val[e] = f2bf(bf2f(val[e]) * rl);
        *(u16x8*)(&Ts[r][cc * 8]) = val;
    }
    __syncthreads();
    const int d = tid >> 2, lc = (tid & 3) * 16;
    u16 tmp[16];
    #pragma unroll
    for (int e = 0; e < 16; ++e) tmp[e] = Ts[lc + e][d];
    u16* dst = Vt + ((size_t)bh * HD_ + d) * L_ + l0 + (lc & 32) + ((lc >> 4) & 1) * 4;
    #pragma unroll
    for (int qd = 0; qd < 4; ++qd) {
        u16x4 o;
        #pragma unroll
        for (int e = 0; e < 4; ++e) o[e] = tmp[qd * 4 + e];
        *(u16x4*)(dst + qd * 8) = o;
    }
}

// ---------------------------------------------------------------------------
// Pass B: O^T = V'^T · P^T, P = exp2(s~) in registers. 128 q/block,
// wave = 64 keys x 32-q slice. 48 KB LDS -> 3 blocks/CU.
// 1-D grid 768 = 8 XCD x (6 bh x 16 q-blocks): same-bh K/V stream per XCD.
// ---------------------------------------------------------------------------
__global__ __launch_bounds__(256, 3) void attn_out(
    const u16* __restrict__ Qb, const u16* __restrict__ Kb,
    const u16* __restrict__ Vt, u16* __restrict__ Ob)
{
    __shared__ __align__(16) u16 Qs[128 * 64];     // 16 KB: Q staging -> O epilogue
    __shared__ __align__(16) u16 Ks[2][64 * 64];   // 16 KB dbuf
    __shared__ __align__(16) u16 Vts[2][64 * 64];  // 16 KB dbuf
    const int tid  = threadIdx.x;
    const int lane = tid & 63, w = tid >> 6;
    const int s    = lane & 15, quad = lane >> 4;
    const int s7   = s & 7;
    const int bid  = blockIdx.x;
    const int xcd  = bid & 7, j0 = bid >> 3;       // j0 in 0..95
    const int bh   = xcd * 6 + j0 / 16;
    const int qbase = (j0 % 16) * 128;
    const int b    = bh / NH_, h = bh % NH_;
    const int qw   = w * 32;                        // this wave's 32-q slice
    const u16* Qg = Qb + (size_t)b * L_ * D_ + h * HD_;
    const u16* Kg = Kb + (size_t)b * L_ * D_ + h * HD_;
    const u16* Vg = Vt + (size_t)bh * HD_ * L_;
    const int wb = tid & ~63;

    // stage Q (1024 chunks, 4/thread) + preload K/V tile 0
    #pragma unroll
    for (int c0 = 0; c0 < 1024; c0 += 256) {
        int c = c0 + tid, r = c >> 3, cc = (c & 7) ^ (r & 7);
        gld16(Qg + (size_t)(qbase + r) * D_ + cc * 8, Qs + (size_t)(c0 + wb) * 8);
    }
    {
        int c = tid, r = c >> 3, cc = (c & 7) ^ (r & 7);
        gld16(Kg + (size_t)r * D_ + cc * 8, Ks[0] + (size_t)wb * 8);
        gld16(Vg + (size_t)r * L_ + cc * 8, Vts[0] + (size_t)wb * 8);
        c = tid + 256; r = c >> 3; cc = (c & 7) ^ (r & 7);
        gld16(Kg + (size_t)r * D_ + cc * 8, Ks[0] + (size_t)(wb + 256) * 8);
        gld16(Vg + (size_t)r * L_ + cc * 8, Vts[0] + (size_t)(wb + 256) * 8);
    }
    __syncthreads();
    // hoist Q B-frags (loop-invariant), j over 2 q-tiles of 16
    bf16x8 qf[2][2];
    #pragma unroll
    for (int kk = 0; kk < 2; ++kk)
        #pragma unroll
        for (int j = 0; j < 2; ++j)
            qf[kk][j] = *(const bf16x8*)(Qs + (qw + j * 16 + s) * 64 +
                                         ((kk * 4 + quad) ^ s7) * 8);
    f32x4 acc_o[4][2];
    #pragma unroll
    for (int i = 0; i < 4; ++i)
        #pragma unroll
        for (int j = 0; j < 2; ++j) acc_o[i][j] = (f32x4){0.f, 0.f, 0.f, 0.f};

    for (int t = 0; t < 32; ++t) {
        const u16* Kt  = Ks[t & 1];
        const u16* Vtt = Vts[t & 1];
        if (t < 31) {
            const int kn = (t + 1) * 64;
            u16* Kd = Ks[(t + 1) & 1];
            u16* Vd = Vts[(t + 1) & 1];
            int c = tid, r = c >> 3, cc = (c & 7) ^ (r & 7);
            gld16(Kg + (size_t)(kn + r) * D_ + cc * 8, Kd + (size_t)wb * 8);
            gld16(Vg + (size_t)r * L_ + kn + cc * 8,   Vd + (size_t)wb * 8);
            c = tid + 256; r = c >> 3; cc = (c & 7) ^ (r & 7);
            gld16(Kg + (size_t)(kn + r) * D_ + cc * 8, Kd + (size_t)(wb + 256) * 8);
            gld16(Vg + (size_t)r * L_ + kn + cc * 8,   Vd + (size_t)(wb + 256) * 8);
        }
        // ---- S: 64 keys x 32 queries (this wave's slice) ----
        f32x4 acc_s[4][2];
        #pragma unroll
        for (int i = 0; i < 4; ++i)
            #pragma unroll
            for (int j = 0; j < 2; ++j) acc_s[i][j] = (f32x4){0.f, 0.f, 0.f, 0.f};
        #pragma unroll
        for (int kk = 0; kk < 2; ++kk) {
            bf16x8 kfr[4];
            #pragma unroll
            for (int i = 0; i < 4; ++i)
                kfr[i] = *(const bf16x8*)(Kt + (i * 16 + s) * 64 +
                                          ((kk * 4 + quad) ^ s7) * 8);
            #pragma unroll
            for (int i = 0; i < 4; ++i)
                #pragma unroll
                for (int j = 0; j < 2; ++j)
                    acc_s[i][j] = __builtin_amdgcn_mfma_f32_16x16x32_bf16(
                        kfr[i], qf[kk][j], acc_s[i][j], 0, 0, 0);
        }
        // ---- P = exp2(s~), packed bf16 pairs (register only) ----
        unsigned pk[4][2][2];
        #pragma unroll
        for (int i = 0; i < 4; ++i)
            #pragma unroll
            for (int j = 0; j < 2; ++j) {
                float p0 = ex2(acc_s[i][j][0]), p1 = ex2(acc_s[i][j][1]);
                float p2 = ex2(acc_s[i][j][2]), p3 = ex2(acc_s[i][j][3]);
                pk[i][j][0] = packbf(p0, p1);
                pk[i][j][1] = packbf(p2, p3);
            }
        // ---- O^T += V'^T · P^T (B-frags = register renames of pk) ----
        #pragma unroll
        for (int kk = 0; kk < 2; ++kk) {
            bf16x8 av[4];
            #pragma unroll
            for (int i = 0; i < 4; ++i)
                av[i] = *(const bf16x8*)(Vtt + (i * 16 + s) * 64 +
                                         ((kk * 4 + quad) ^ s7) * 8);
            #pragma unroll
            for (int j = 0; j < 2; ++j) {
                union { unsigned u[4]; bf16x8 v; } bu;
                bu.u[0] = pk[2 * kk][j][0];
                bu.u[1] = pk[2 * kk][j][1];
                bu.u[2] = pk[2 * kk + 1][j][0];
                bu.u[3] = pk[2 * kk + 1][j][1];
                #pragma unroll
                for (int i = 0; i < 4; ++i)
                    acc_o[i][j] = __builtin_amdgcn_mfma_f32_16x16x32_bf16(
                        av[i], bu.v, acc_o[i][j], 0, 0, 0);
            }
        }
        __syncthreads();
    }
    // ---- epilogue: O^T -> Qs as [128 q][64 d] (swizzled) -> coalesced store
    #pragma unroll
    for (int i = 0; i < 4; ++i) {
        const int dchunk = i * 2 + (quad >> 1), doff = (quad & 1) * 4;
        #pragma unroll
        for (int j = 0; j < 2; ++j) {
            const int q = qw + j * 16 + s;
            u16x4 ov;
            #pragma unroll
            for (int r = 0; r < 4; ++r) ov[r] = f2bf(acc_o[i][j][r]);
            *(u16x4*)(Qs + q * 64 + (dchunk ^ s7) * 8 + doff) = ov;
        }
    }
    __syncthreads();
    {
        const int q = tid >> 1, half = tid & 1, q7 = q & 7;
        u16* dst = Ob + (size_t)(b * L_ + qbase + q) * D_ + h * HD_ + half * 32;
        #pragma unroll
        for (int c = 0; c < 4; ++c) {
            const int cn = half * 4 + c;
            u16x8 v = *(const u16x8*)(Qs + q * 64 + ((cn ^ q7) * 8));
            *(u16x8*)(dst + c * 8) = v;
        }
    }
}

// ---------------------------------------------------------------------------
extern "C" void kernel_launch(void* const* d_in, const int* in_sizes, int n_in,
                              void* d_out, int out_size, void* d_ws, size_t ws_size,
                              hipStream_t stream)
{
    const float* x  = (const float*)d_in[0];
    const float* Wq = (const float*)d_in[1];
    const float* Wk = (const float*)d_in[2];
    const float* bk = (const float*)d_in[3];
    const float* Wv = (const float*)d_in[4];
    const float* bv = (const float*)d_in[5];
    const float* gq = (const float*)d_in[6];
    const float* gk = (const float*)d_in[7];
    const float* Wo = (const float*)d_in[8];
    const float* bo = (const float*)d_in[9];
    float* out = (float*)d_out;

    char* p = (char*)d_ws;
    u16* xb   = (u16*)p;  p += (size_t)M_ * D_ * 2;
    u16* qpre = (u16*)p;  p += (size_t)M_ * D_ * 2;   // ob aliases after LN
    u16* kpre = (u16*)p;  p += (size_t)M_ * D_ * 2;   // vt aliases after LN
    u16* vb   = (u16*)p;  p += (size_t)M_ * D_ * 2;
    u16* qb   = (u16*)p;  p += (size_t)M_ * D_ * 2;
    u16* kb   = (u16*)p;  p += (size_t)M_ * D_ * 2;
    u16* wqb  = (u16*)p;  p += (size_t)D_ * D_ * 2;
    u16* wkb  = (u16*)p;  p += (size_t)D_ * D_ * 2;
    u16* wvb  = (u16*)p;  p += (size_t)D_ * D_ * 2;
    u16* wob  = (u16*)p;  p += (size_t)D_ * D_ * 2;
    float* Rl = (float*)p; p += (size_t)B_ * NH_ * L_ * 4;
    u16* ob = qpre;   // dead after LN
    u16* vt = kpre;   // dead after LN

    const int nX = M_ * D_, nW = D_ * D_;
    cvt_bf16_kernel<<<nX / 2048, 256, 0, stream>>>(x, xb, nX / 8);
    cvt4_bf16_kernel<<<dim3(nW / 2048, 4), 256, 0, stream>>>(
        Wq, Wk, Wv, Wo, wqb, wkb, wvb, wob, nW / 8);

    gemm_qkv<<<1152, 256, 0, stream>>>(
        xb, wqb, wkb, wvb, bk, bv, qpre, kpre, vb);

    ln_bf16<<<M_, 256, 0, stream>>>(qpre, gq, qb, SC2);
    ln_bf16<<<M_, 256, 0, stream>>>(kpre, gk, kb, 1.0f);

    attn_stats<<<768, 256, 0, stream>>>(qb, kb, Rl);
    transpose_v_scaled<<<dim3(L_ / 64, NH_, B_), 256, 0, stream>>>(vb, Rl, vt);
    attn_out<<<768, 256, 0, stream>>>(qb, kb, vt, ob);

    gemm_final<<<384, 256, 0, stream>>>(ob, wob, bo, x, out);
}

// Round 9
// 281.208 us; speedup vs baseline: 1.1585x; 1.0329x over previous
//
#include <hip/hip_runtime.h>
#include <cstddef>
#include <cstdint>

// ---------------------------------------------------------------------------
// MultiheadSelfAttn (b=4, l=2048, d=768, nh=12, hd=64), softmax over QUERY axis.
// cvt (single launch) -> fused QKV GEMM (dbuf, C^T, bf16 LDS epilogue,
// launch_bounds(256,4) for 4 blocks/CU -> 1.125 residency rounds) ->
// LN x2-in-one (SC2 folded into q) -> stats (no-max exp2 sum) ->
// V transpose (*1/l, PV key-permuted) -> attention out (register-P) ->
// final GEMM. XCD-aware 1-D grid swizzle on all heavy kernels.
// ---------------------------------------------------------------------------

typedef unsigned short u16;
typedef short  bf16x8 __attribute__((ext_vector_type(8)));   // MFMA A/B frag
typedef float  f32x4  __attribute__((ext_vector_type(4)));   // MFMA C/D frag
typedef unsigned short u16x8 __attribute__((ext_vector_type(8)));
typedef unsigned short u16x4 __attribute__((ext_vector_type(4)));

#define B_   4
#define L_   2048
#define D_   768
#define NH_  12
#define HD_  64
#define M_   (B_*L_)
#define SC2  (0.125f * 1.44269504088896f)   // scale * log2(e), folded into qb

__device__ __forceinline__ float ex2(float x) { return __builtin_amdgcn_exp2f(x); }

__device__ __forceinline__ u16 f2bf(float f) {            // RNE
    union { float f; unsigned u; } v; v.f = f;
    unsigned r = v.u + 0x7FFFu + ((v.u >> 16) & 1u);
    return (u16)(r >> 16);
}
__device__ __forceinline__ float bf2f(u16 b) {
    union { unsigned u; float f; } v; v.u = ((unsigned)b) << 16;
    return v.f;
}
__device__ __forceinline__ unsigned fbits(float f) {
    union { float f; unsigned u; } v; v.f = f; return v.u;
}
// pack two f32 -> (bf16(lo) | bf16(hi)<<16), truncation (P>=0, slack ok)
__device__ __forceinline__ unsigned packbf(float lo, float hi) {
    return __builtin_amdgcn_perm(fbits(hi), fbits(lo), 0x07060302u);
}

// async global->LDS, 16B/lane; LDS dest = wave-uniform base + lane*16.
__device__ __forceinline__ void gld16(const void* g, void* l) {
    __builtin_amdgcn_global_load_lds(
        (const __attribute__((address_space(1))) unsigned*)g,
        (__attribute__((address_space(3))) unsigned*)l, 16, 0, 0);
}

// ---------------------------------------------------------------------------
// fp32 -> bf16 bulk convert: x + 4 weights in ONE launch (flat chunk index).
// ---------------------------------------------------------------------------
__global__ __launch_bounds__(256) void cvt_all(
    const float* __restrict__ X,
    const float* __restrict__ W0, const float* __restrict__ W1,
    const float* __restrict__ W2, const float* __restrict__ W3,
    u16* __restrict__ Yx,
    u16* __restrict__ Y0, u16* __restrict__ Y1,
    u16* __restrict__ Y2, u16* __restrict__ Y3)
{
    const int nX8 = (M_ * D_) / 8;      // 786432
    const int nW8 = (D_ * D_) / 8;      // 73728
    int i = blockIdx.x * 256 + threadIdx.x;
    if (i >= nX8 + 4 * nW8) return;
    const float* S; u16* Dst; int off;
    if (i < nX8) { S = X; Dst = Yx; off = i; }
    else {
        int j = i - nX8;
        int w = j / nW8; off = j - w * nW8;
        S   = (w == 0) ? W0 : (w == 1) ? W1 : (w == 2) ? W2 : W3;
        Dst = (w == 0) ? Y0 : (w == 1) ? Y1 : (w == 2) ? Y2 : Y3;
    }
    const float4* xp = (const float4*)S + (size_t)off * 2;
    float4 a = xp[0], b = xp[1];
    u16x8 o;
    o[0] = f2bf(a.x); o[1] = f2bf(a.y); o[2] = f2bf(a.z); o[3] = f2bf(a.w);
    o[4] = f2bf(b.x); o[5] = f2bf(b.y); o[6] = f2bf(b.z); o[7] = f2bf(b.w);
    *((u16x8*)Dst + off) = o;
}

// ---------------------------------------------------------------------------
// Fused QKV GEMM: A[8192,768] x {Wq,Wk,Wv}^T -> bf16. 128x128 tile, BK=32,
// dbuf (1 barrier/iter), BK-swizzled LDS, C^T accumulate, bf16 LDS epilogue.
// 1-D grid 1152 = 8 XCD x (8 bm x 18 seg/bn). launch_bounds(256,4): cap
// unified regs at 128 -> 4 blocks/CU -> 1.125 residency rounds (was 1.5).
// ---------------------------------------------------------------------------
__global__ __launch_bounds__(256, 4) void gemm_qkv(
    const u16* __restrict__ A,
    const u16* __restrict__ W0, const u16* __restrict__ W1,
    const u16* __restrict__ W2,
    const float* __restrict__ bk, const float* __restrict__ bv,
    u16* __restrict__ q_o, u16* __restrict__ k_o, u16* __restrict__ v_o)
{
    __shared__ __align__(16) u16 lds[16384];   // [A0|A1|B0|B1] 4x8KB -> Ct 32KB
    __shared__ float bs[128];
    const int tid  = threadIdx.x;
    const int lane = tid & 63, w = tid >> 6;
    const int s    = lane & 15, quad = lane >> 4;
    const int bid  = blockIdx.x;
    const int xcd  = bid & 7, j0 = bid >> 3;       // j0 in 0..143
    const int bm   = (xcd * 8 + j0 / 18) * 128;
    const int sub  = j0 % 18;
    const int seg  = sub / 6;
    const int bn   = (sub % 6) * 128;
    const u16* W = (seg == 0) ? W0 : ((seg == 1) ? W1 : W2);
    u16* OUT = (seg == 0) ? q_o : ((seg == 1) ? k_o : v_o);
    const int mh = (w >> 1) * 64, nh = (w & 1) * 64;
    const int wb = tid & ~63;
    const int cq = quad ^ ((s >> 1) & 3);      // swizzled frag chunk

    if (tid < 128)
        bs[tid] = (seg == 1) ? bk[bn + tid] : ((seg == 2) ? bv[bn + tid] : 0.0f);

    f32x4 acc[4][4];   // [j (n-tile)][i (m-tile)], C^T
    #pragma unroll
    for (int j = 0; j < 4; ++j)
        #pragma unroll
        for (int i = 0; i < 4; ++i) acc[j][i] = (f32x4){0.f, 0.f, 0.f, 0.f};

    {
        int c = tid, r = c >> 2, cs = (c & 3) ^ ((r >> 1) & 3);
        gld16(A + (size_t)(bm + r) * D_ + cs * 8, lds + (size_t)wb * 8);
        gld16(W + (size_t)(bn + r) * D_ + cs * 8, lds + 8192 + (size_t)wb * 8);
        c = tid + 256; r = c >> 2; cs = (c & 3) ^ ((r >> 1) & 3);
        gld16(A + (size_t)(bm + r) * D_ + cs * 8, lds + (size_t)(wb + 256) * 8);
        gld16(W + (size_t)(bn + r) * D_ + cs * 8, lds + 8192 + (size_t)(wb + 256) * 8);
    }
    __syncthreads();

    for (int t = 0; t < 24; ++t) {
        const u16* Ab = lds + (t & 1) * 4096;
        const u16* Bb = lds + 8192 + (t & 1) * 4096;
        if (t < 23) {
            const int k0 = (t + 1) * 32;
            u16* Ad = lds + ((t + 1) & 1) * 4096;
            u16* Bd = lds + 8192 + ((t + 1) & 1) * 4096;
            int c = tid, r = c >> 2, cs = (c & 3) ^ ((r >> 1) & 3);
            gld16(A + (size_t)(bm + r) * D_ + k0 + cs * 8, Ad + (size_t)wb * 8);
            gld16(W + (size_t)(bn + r) * D_ + k0 + cs * 8, Bd + (size_t)wb * 8);
            c = tid + 256; r = c >> 2; cs = (c & 3) ^ ((r >> 1) & 3);
            gld16(A + (size_t)(bm + r) * D_ + k0 + cs * 8, Ad + (size_t)(wb + 256) * 8);
            gld16(W + (size_t)(bn + r) * D_ + k0 + cs * 8, Bd + (size_t)(wb + 256) * 8);
        }
        bf16x8 af[4], bf[4];
        #pragma unroll
        for (int i = 0; i < 4; ++i)
            af[i] = *(const bf16x8*)(Ab + (mh + i * 16 + s) * 32 + cq * 8);
        #pragma unroll
        for (int j = 0; j < 4; ++j)
            bf[j] = *(const bf16x8*)(Bb + (nh + j * 16 + s) * 32 + cq * 8);
        #pragma unroll
        for (int j = 0; j < 4; ++j)
            #pragma unroll
            for (int i = 0; i < 4; ++i)
                acc[j][i] = __builtin_amdgcn_mfma_f32_16x16x32_bf16(
                    bf[j], af[i], acc[j][i], 0, 0, 0);   // C^T: rows=n, cols=m
        __syncthreads();
    }
    // epilogue: bf16 + bias -> Ct[m][128] (chunk ^ (m&15)) -> coalesced store
    u16* Ct = lds;
    #pragma unroll
    for (int j = 0; j < 4; ++j) {
        const int n0 = nh + j * 16 + quad * 4;
        const f32x4 b4 = *(const f32x4*)(bs + n0);
        const int cn = n0 >> 3, off = n0 & 7;
        #pragma unroll
        for (int i = 0; i < 4; ++i) {
            const int m = mh + i * 16 + s;
            u16x4 ov;
            #pragma unroll
            for (int r = 0; r < 4; ++r) ov[r] = f2bf(acc[j][i][r] + b4[r]);
            *(u16x4*)(Ct + m * 128 + ((cn ^ (m & 15)) * 8) + off) = ov;
        }
    }
    __syncthreads();
    {
        const int m = tid >> 1, half = tid & 1;
        u16* dst = OUT + (size_t)(bm + m) * D_ + bn + half * 64;
        #pragma unroll
        for (int cc = 0; cc < 8; ++cc) {
            const int cn = half * 8 + cc;
            u16x8 v = *(const u16x8*)(Ct + m * 128 + ((cn ^ (m & 15)) * 8));
            *(u16x8*)(dst + cc * 8) = v;
        }
    }
}

// ---------------------------------------------------------------------------
// Final GEMM: out = ob @ Wo^T + bo + x (fp32 out). dbuf + C^T + float4 stores.
// 1-D grid 384 = 8 XCD x (8 bm x 6 bn); (256,3) pins zero-tail residency.
// ---------------------------------------------------------------------------
__global__ __launch_bounds__(256, 3) void gemm_final(
    const u16* __restrict__ A, const u16* __restrict__ W,
    const float* __restrict__ bias, const float* __restrict__ resid,
    float* __restrict__ outf)
{
    __shared__ __align__(16) u16 lds[16384];
    const int tid  = threadIdx.x;
    const int lane = tid & 63, w = tid >> 6;
    const int s    = lane & 15, quad = lane >> 4;
    const int bid  = blockIdx.x;
    const int xcd  = bid & 7, j0 = bid >> 3;       // j0 in 0..47
    const int bm   = (xcd * 8 + j0 / 6) * 128;
    const int bn   = (j0 % 6) * 128;
    const int mh   = (w >> 1) * 64, nh = (w & 1) * 64;
    const int wb   = tid & ~63;
    const int cq   = quad ^ ((s >> 1) & 3);
    f32x4 acc[4][4];
    #pragma unroll
    for (int j = 0; j < 4; ++j)
        #pragma unroll
        for (int i = 0; i < 4; ++i) acc[j][i] = (f32x4){0.f, 0.f, 0.f, 0.f};

    {
        int c = tid, r = c >> 2, cs = (c & 3) ^ ((r >> 1) & 3);
        gld16(A + (size_t)(bm + r) * D_ + cs * 8, lds + (size_t)wb * 8);
        gld16(W + (size_t)(bn + r) * D_ + cs * 8, lds + 8192 + (size_t)wb * 8);
        c = tid + 256; r = c >> 2; cs = (c & 3) ^ ((r >> 1) & 3);
        gld16(A + (size_t)(bm + r) * D_ + cs * 8, lds + (size_t)(wb + 256) * 8);
        gld16(W + (size_t)(bn + r) * D_ + cs * 8, lds + 8192 + (size_t)(wb + 256) * 8);
    }
    __syncthreads();

    for (int t = 0; t < 24; ++t) {
        const u16* Ab = lds + (t & 1) * 4096;
        const u16* Bb = lds + 8192 + (t & 1) * 4096;
        if (t < 23) {
            const int k0 = (t + 1) * 32;
            u16* Ad = lds + ((t + 1) & 1) * 4096;
            u16* Bd = lds + 8192 + ((t + 1) & 1) * 4096;
            int c = tid, r = c >> 2, cs = (c & 3) ^ ((r >> 1) & 3);
            gld16(A + (size_t)(bm + r) * D_ + k0 + cs * 8, Ad + (size_t)wb * 8);
            gld16(W + (size_t)(bn + r) * D_ + k0 + cs * 8, Bd + (size_t)wb * 8);
            c = tid + 256; r = c >> 2; cs = (c & 3) ^ ((r >> 1) & 3);
            gld16(A + (size_t)(bm + r) * D_ + k0 + cs * 8, Ad + (size_t)(wb + 256) * 8);
            gld16(W + (size_t)(bn + r) * D_ + k0 + cs * 8, Bd + (size_t)(wb + 256) * 8);
        }
        bf16x8 af[4], bf[4];
        #pragma unroll
        for (int i = 0; i < 4; ++i)
            af[i] = *(const bf16x8*)(Ab + (mh + i * 16 + s) * 32 + cq * 8);
        #pragma unroll
        for (int j = 0; j < 4; ++j)
            bf[j] = *(const bf16x8*)(Bb + (nh + j * 16 + s) * 32 + cq * 8);
        #pragma unroll
        for (int j = 0; j < 4; ++j)
            #pragma unroll
            for (int i = 0; i < 4; ++i)
                acc[j][i] = __builtin_amdgcn_mfma_f32_16x16x32_bf16(
                    bf[j], af[i], acc[j][i], 0, 0, 0);
        __syncthreads();
    }
    #pragma unroll
    for (int j = 0; j < 4; ++j) {
        const int n0 = nh + j * 16 + quad * 4;
        const float4 b4 = *(const float4*)(bias + bn + n0);
        #pragma unroll
        for (int i = 0; i < 4; ++i) {
            const int m = mh + i * 16 + s;
            const size_t base = (size_t)(bm + m) * D_ + bn + n0;
            const float4 rs = *(const float4*)(resid + base);
            float4 o;
            o.x = acc[j][i][0] + b4.x + rs.x;
            o.y = acc[j][i][1] + b4.y + rs.y;
            o.z = acc[j][i][2] + b4.z + rs.z;
            o.w = acc[j][i][3] + b4.w + rs.w;
            *(float4*)(outf + base) = o;
        }
    }
}

// ---------------------------------------------------------------------------
// Row LayerNorm (pop var, eps 1e-5) * gamma * scale, bf16 in -> bf16 out.
// Both q (scale=SC2) and k (scale=1) in one launch via blockIdx.y.
// ---------------------------------------------------------------------------
__global__ __launch_bounds__(256) void ln2_bf16(
    const u16* __restrict__ Q, const u16* __restrict__ K,
    const float* __restrict__ gq, const float* __restrict__ gk,
    u16* __restrict__ Yq, u16* __restrict__ Yk)
{
    const int row = blockIdx.x;
    const int which = blockIdx.y;
    const u16* x = (which ? K : Q) + (size_t)row * D_;
    const float* gamma = which ? gk : gq;
    u16* Y = which ? Yk : Yq;
    const float scale = which ? 1.0f : (float)SC2;
    const int tid = threadIdx.x;
    float v[3];
    float lsum = 0.f, lsq = 0.f;
    #pragma unroll
    for (int e = 0; e < 3; ++e) {
        float t = bf2f(x[tid + e * 256]);
        v[e] = t; lsum += t; lsq += t * t;
    }
    #pragma unroll
    for (int off = 32; off > 0; off >>= 1) {
        lsum += __shfl_down(lsum, off);
        lsq  += __shfl_down(lsq,  off);
    }
    __shared__ float s1[4], s2[4];
    const int wv = tid >> 6, lane = tid & 63;
    if (lane == 0) { s1[wv] = lsum; s2[wv] = lsq; }
    __syncthreads();
    const float sum = s1[0] + s1[1] + s1[2] + s1[3];
    const float sq  = s2[0] + s2[1] + s2[2] + s2[3];
    const float mu  = sum * (1.0f / D_);
    const float var = sq * (1.0f / D_) - mu * mu;
    const float inv = rsqrtf(var + 1e-5f) * scale;
    #pragma unroll
    for (int e = 0; e < 3; ++e) {
        int c = tid + e * 256;
        Y[(size_t)row * D_ + c] = f2bf((v[e] - mu) * inv * gamma[c]);
    }
}

// ---------------------------------------------------------------------------
// Pass A: per-key l = sum_q exp2(s~[q,k]) (NO max: QK-norm bounds scores).
// 1-D grid 768 = 8 XCD x (6 bh x 16 k-blocks); (256,3) -> zero-tail 3/CU.
// ---------------------------------------------------------------------------
__global__ __launch_bounds__(256, 3) void attn_stats(
    const u16* __restrict__ Qb, const u16* __restrict__ Kb,
    float* __restrict__ Rl)
{
    __shared__ __align__(16) u16 Ks[128 * 64];       // 16 KB
    __shared__ __align__(16) u16 Qs[2][128 * 64];    // 32 KB dbuf
    __shared__ float lbuf[4][64];
    const int tid  = threadIdx.x;
    const int lane = tid & 63, w = tid >> 6;
    const int s    = lane & 15, quad = lane >> 4;
    const int s7   = s & 7;
    const int bid  = blockIdx.x;
    const int xcd  = bid & 7, j0 = bid >> 3;       // j0 in 0..95
    const int bh   = xcd * 6 + j0 / 16;
    const int kbase = (j0 % 16) * 128;
    const int b    = bh / NH_, h = bh % NH_;
    const u16* Qg = Qb + (size_t)b * L_ * D_ + h * HD_;
    const u16* Kg = Kb + (size_t)b * L_ * D_ + h * HD_;
    const int mh = (w >> 1) * 64;   // key half
    const int nh = (w & 1) * 64;    // query half
    const int wb = tid & ~63;

    #pragma unroll
    for (int c0 = 0; c0 < 1024; c0 += 256) {
        int c = c0 + tid, r = c >> 3, cc = (c & 7) ^ (r & 7);
        gld16(Kg + (size_t)(kbase + r) * D_ + cc * 8, Ks + (size_t)(c0 + wb) * 8);
        gld16(Qg + (size_t)r * D_ + cc * 8, Qs[0] + (size_t)(c0 + wb) * 8);
    }
    __syncthreads();
    bf16x8 kf[2][4];
    #pragma unroll
    for (int kk = 0; kk < 2; ++kk)
        #pragma unroll
        for (int i = 0; i < 4; ++i)
            kf[kk][i] = *(const bf16x8*)(Ks + (mh + i * 16 + s) * 64 +
                                         ((kk * 4 + quad) ^ s7) * 8);
    float lacc[4][4];
    #pragma unroll
    for (int i = 0; i < 4; ++i)
        #pragma unroll
        for (int r = 0; r < 4; ++r) lacc[i][r] = 0.f;

    for (int t = 0; t < 16; ++t) {
        if (t < 15) {
            const int qn = (t + 1) * 128;
            u16* Qd = Qs[(t + 1) & 1];
            #pragma unroll
            for (int c0 = 0; c0 < 1024; c0 += 256) {
                int c = c0 + tid, r = c >> 3, cc = (c & 7) ^ (r & 7);
                gld16(Qg + (size_t)(qn + r) * D_ + cc * 8, Qd + (size_t)(c0 + wb) * 8);
            }
        }
        const u16* Qt = Qs[t & 1];
        f32x4 acc[4][4];
        #pragma unroll
        for (int i = 0; i < 4; ++i)
            #pragma unroll
            for (int j = 0; j < 4; ++j) acc[i][j] = (f32x4){0.f, 0.f, 0.f, 0.f};
        #pragma unroll
        for (int kk = 0; kk < 2; ++kk) {
            bf16x8 bf[4];
            #pragma unroll
            for (int j = 0; j < 4; ++j)
                bf[j] = *(const bf16x8*)(Qt + (nh + j * 16 + s) * 64 +
                                         ((kk * 4 + quad) ^ s7) * 8);
            #pragma unroll
            for (int i = 0; i < 4; ++i)
                #pragma unroll
                for (int j = 0; j < 4; ++j)
                    acc[i][j] = __builtin_amdgcn_mfma_f32_16x16x32_bf16(
                        kf[kk][i], bf[j], acc[i][j], 0, 0, 0);
        }
        #pragma unroll
        for (int i = 0; i < 4; ++i)
            #pragma unroll
            for (int r = 0; r < 4; ++r) {
                float l0 = ex2(acc[i][0][r]) + ex2(acc[i][1][r]);
                float l1 = ex2(acc[i][2][r]) + ex2(acc[i][3][r]);
                lacc[i][r] += l0 + l1;
            }
        __syncthreads();
    }
    #pragma unroll
    for (int i = 0; i < 4; ++i)
        #pragma unroll
        for (int r = 0; r < 4; ++r) {
            float v = lacc[i][r];
            #pragma unroll
            for (int d2 = 1; d2 < 16; d2 <<= 1) v += __shfl_xor(v, d2);
            lacc[i][r] = v;
        }
    if (s == 0) {
        #pragma unroll
        for (int i = 0; i < 4; ++i)
            #pragma unroll
            for (int r = 0; r < 4; ++r)
                lbuf[w][i * 16 + quad * 4 + r] = lacc[i][r];
    }
    __syncthreads();
    if (tid < 128) {
        int kh = tid >> 6, kl = tid & 63;
        float l = lbuf[kh * 2][kl] + lbuf[kh * 2 + 1][kl];
        Rl[(size_t)bh * L_ + kbase + tid] = 1.0f / l;
    }
}

// ---------------------------------------------------------------------------
// V transpose + fold 1/l + PV key-permutation (p = ((a>>2)&3)*8+((a>>4)&1)*4+(a&3))
// ---------------------------------------------------------------------------
__global__ __launch_bounds__(256) void transpose_v_scaled(
    const u16* __restrict__ Vb, const float* __restrict__ Rl,
    u16* __restrict__ Vt)
{
    const int l0 = blockIdx.x * 64, h = blockIdx.y, b = blockIdx.z;
    const int bh = b * NH_ + h;
    __shared__ __align__(16) u16 Ts[64][72];
    const int tid = threadIdx.x;
    #pragma unroll
    for (int c = tid; c < 512; c += 256) {
        int r = c >> 3, cc = c & 7;
        u16x8 val = *(const u16x8*)(Vb + (size_t)(b * L_ + l0 + r) * D_ + h * HD_ + cc * 8);
        const float rl = Rl[(size_t)bh * L_ + l0 + r];
        #pragma unroll
        for (int e = 0; e < 8; ++e) val[e] = f2bf(bf2f(val[e]) * rl);
        *(u16x8*)(&Ts[r][cc * 8]) = val;
    }
    __syncthreads();
    const int d = tid >> 2, lc = (tid & 3) * 16;
    u16 tmp[16];
    #pragma unroll
    for (int e = 0; e < 16; ++e) tmp[e] = Ts[lc + e][d];
    u16* dst = Vt + ((size_t)bh * HD_ + d) * L_ + l0 + (lc & 32) + ((lc >> 4) & 1) * 4;
    #pragma unroll
    for (int qd = 0; qd < 4; ++qd) {
        u16x4 o;
        #pragma unroll
        for (int e = 0; e < 4; ++e) o[e] = tmp[qd * 4 + e];
        *(u16x4*)(dst + qd * 8) = o;
    }
}

// ---------------------------------------------------------------------------
// Pass B: O^T = V'^T · P^T, P = exp2(s~) in registers. 128 q/block,
// wave = 64 keys x 32-q slice. 48 KB LDS -> 3 blocks/CU (zero tail at 768).
// ---------------------------------------------------------------------------
__global__ __launch_bounds__(256, 3) void attn_out(
    const u16* __restrict__ Qb, const u16* __restrict__ Kb,
    const u16* __restrict__ Vt, u16* __restrict__ Ob)
{
    __shared__ __align__(16) u16 Qs[128 * 64];     // 16 KB: Q staging -> O epilogue
    __shared__ __align__(16) u16 Ks[2][64 * 64];   // 16 KB dbuf
    __shared__ __align__(16) u16 Vts[2][64 * 64];  // 16 KB dbuf
    const int tid  = threadIdx.x;
    const int lane = tid & 63, w = tid >> 6;
    const int s    = lane & 15, quad = lane >> 4;
    const int s7   = s & 7;
    const int bid  = blockIdx.x;
    const int xcd  = bid & 7, j0 = bid >> 3;       // j0 in 0..95
    const int bh   = xcd * 6 + j0 / 16;
    const int qbase = (j0 % 16) * 128;
    const int b    = bh / NH_, h = bh % NH_;
    const int qw   = w * 32;                        // this wave's 32-q slice
    const u16* Qg = Qb + (size_t)b * L_ * D_ + h * HD_;
    const u16* Kg = Kb + (size_t)b * L_ * D_ + h * HD_;
    const u16* Vg = Vt + (size_t)bh * HD_ * L_;
    const int wb = tid & ~63;

    // stage Q (1024 chunks, 4/thread) + preload K/V tile 0
    #pragma unroll
    for (int c0 = 0; c0 < 1024; c0 += 256) {
        int c = c0 + tid, r = c >> 3, cc = (c & 7) ^ (r & 7);
        gld16(Qg + (size_t)(qbase + r) * D_ + cc * 8, Qs + (size_t)(c0 + wb) * 8);
    }
    {
        int c = tid, r = c >> 3, cc = (c & 7) ^ (r & 7);
        gld16(Kg + (size_t)r * D_ + cc * 8, Ks[0] + (size_t)wb * 8);
        gld16(Vg + (size_t)r * L_ + cc * 8, Vts[0] + (size_t)wb * 8);
        c = tid + 256; r = c >> 3; cc = (c & 7) ^ (r & 7);
        gld16(Kg + (size_t)r * D_ + cc * 8, Ks[0] + (size_t)(wb + 256) * 8);
        gld16(Vg + (size_t)r * L_ + cc * 8, Vts[0] + (size_t)(wb + 256) * 8);
    }
    __syncthreads();
    // hoist Q B-frags (loop-invariant), j over 2 q-tiles of 16
    bf16x8 qf[2][2];
    #pragma unroll
    for (int kk = 0; kk < 2; ++kk)
        #pragma unroll
        for (int j = 0; j < 2; ++j)
            qf[kk][j] = *(const bf16x8*)(Qs + (qw + j * 16 + s) * 64 +
                                         ((kk * 4 + quad) ^ s7) * 8);
    f32x4 acc_o[4][2];
    #pragma unroll
    for (int i = 0; i < 4; ++i)
        #pragma unroll
        for (int j = 0; j < 2; ++j) acc_o[i][j] = (f32x4){0.f, 0.f, 0.f, 0.f};

    for (int t = 0; t < 32; ++t) {
        const u16* Kt  = Ks[t & 1];
        const u16* Vtt = Vts[t & 1];
        if (t < 31) {
            const int kn = (t + 1) * 64;
            u16* Kd = Ks[(t + 1) & 1];
            u16* Vd = Vts[(t + 1) & 1];
            int c = tid, r = c >> 3, cc = (c & 7) ^ (r & 7);
            gld16(Kg + (size_t)(kn + r) * D_ + cc * 8, Kd + (size_t)wb * 8);
            gld16(Vg + (size_t)r * L_ + kn + cc * 8,   Vd + (size_t)wb * 8);
            c = tid + 256; r = c >> 3; cc = (c & 7) ^ (r & 7);
            gld16(Kg + (size_t)(kn + r) * D_ + cc * 8, Kd + (size_t)(wb + 256) * 8);
            gld16(Vg + (size_t)r * L_ + kn + cc * 8,   Vd + (size_t)(wb + 256) * 8);
        }
        // ---- S: 64 keys x 32 queries (this wave's slice) ----
        f32x4 acc_s[4][2];
        #pragma unroll
        for (int i = 0; i < 4; ++i)
            #pragma unroll
            for (int j = 0; j < 2; ++j) acc_s[i][j] = (f32x4){0.f, 0.f, 0.f, 0.f};
        #pragma unroll
        for (int kk = 0; kk < 2; ++kk) {
            bf16x8 kfr[4];
            #pragma unroll
            for (int i = 0; i < 4; ++i)
                kfr[i] = *(const bf16x8*)(Kt + (i * 16 + s) * 64 +
                                          ((kk * 4 + quad) ^ s7) * 8);
            #pragma unroll
            for (int i = 0; i < 4; ++i)
                #pragma unroll
                for (int j = 0; j < 2; ++j)
                    acc_s[i][j] = __builtin_amdgcn_mfma_f32_16x16x32_bf16(
                        kfr[i], qf[kk][j], acc_s[i][j], 0, 0, 0);
        }
        // ---- P = exp2(s~), packed bf16 pairs (register only) ----
        unsigned pk[4][2][2];
        #pragma unroll
        for (int i = 0; i < 4; ++i)
            #pragma unroll
            for (int j = 0; j < 2; ++j) {
                float p0 = ex2(acc_s[i][j][0]), p1 = ex2(acc_s[i][j][1]);
                float p2 = ex2(acc_s[i][j][2]), p3 = ex2(acc_s[i][j][3]);
                pk[i][j][0] = packbf(p0, p1);
                pk[i][j][1] = packbf(p2, p3);
            }
        // ---- O^T += V'^T · P^T (B-frags = register renames of pk) ----
        #pragma unroll
        for (int kk = 0; kk < 2; ++kk) {
            bf16x8 av[4];
            #pragma unroll
            for (int i = 0; i < 4; ++i)
                av[i] = *(const bf16x8*)(Vtt + (i * 16 + s) * 64 +
                                         ((kk * 4 + quad) ^ s7) * 8);
            #pragma unroll
            for (int j = 0; j < 2; ++j) {
                union { unsigned u[4]; bf16x8 v; } bu;
                bu.u[0] = pk[2 * kk][j][0];
                bu.u[1] = pk[2 * kk][j][1];
                bu.u[2] = pk[2 * kk + 1][j][0];
                bu.u[3] = pk[2 * kk + 1][j][1];
                #pragma unroll
                for (int i = 0; i < 4; ++i)
                    acc_o[i][j] = __builtin_amdgcn_mfma_f32_16x16x32_bf16(
                        av[i], bu.v, acc_o[i][j], 0, 0, 0);
            }
        }
        __syncthreads();
    }
    // ---- epilogue: O^T -> Qs as [128 q][64 d] (swizzled) -> coalesced store
    #pragma unroll
    for (int i = 0; i < 4; ++i) {
        const int dchunk = i * 2 + (quad >> 1), doff = (quad & 1) * 4;
        #pragma unroll
        for (int j = 0; j < 2; ++j) {
            const int q = qw + j * 16 + s;
            u16x4 ov;
            #pragma unroll
            for (int r = 0; r < 4; ++r) ov[r] = f2bf(acc_o[i][j][r]);
            *(u16x4*)(Qs + q * 64 + (dchunk ^ s7) * 8 + doff) = ov;
        }
    }
    __syncthreads();
    {
        const int q = tid >> 1, half = tid & 1, q7 = q & 7;
        u16* dst = Ob + (size_t)(b * L_ + qbase + q) * D_ + h * HD_ + half * 32;
        #pragma unroll
        for (int c = 0; c < 4; ++c) {
            const int cn = half * 4 + c;
            u16x8 v = *(const u16x8*)(Qs + q * 64 + ((cn ^ q7) * 8));
            *(u16x8*)(dst + c * 8) = v;
        }
    }
}

// ---------------------------------------------------------------------------
extern "C" void kernel_launch(void* const* d_in, const int* in_sizes, int n_in,
                              void* d_out, int out_size, void* d_ws, size_t ws_size,
                              hipStream_t stream)
{
    const float* x  = (const float*)d_in[0];
    const float* Wq = (const float*)d_in[1];
    const float* Wk = (const float*)d_in[2];
    const float* bk = (const float*)d_in[3];
    const float* Wv = (const float*)d_in[4];
    const float* bv = (const float*)d_in[5];
    const float* gq = (const float*)d_in[6];
    const float* gk = (const float*)d_in[7];
    const float* Wo = (const float*)d_in[8];
    const float* bo = (const float*)d_in[9];
    float* out = (float*)d_out;

    char* p = (char*)d_ws;
    u16* xb   = (u16*)p;  p += (size_t)M_ * D_ * 2;
    u16* qpre = (u16*)p;  p += (size_t)M_ * D_ * 2;   // ob aliases after LN
    u16* kpre = (u16*)p;  p += (size_t)M_ * D_ * 2;   // vt aliases after LN
    u16* vb   = (u16*)p;  p += (size_t)M_ * D_ * 2;
    u16* qb   = (u16*)p;  p += (size_t)M_ * D_ * 2;
    u16* kb   = (u16*)p;  p += (size_t)M_ * D_ * 2;
    u16* wqb  = (u16*)p;  p += (size_t)D_ * D_ * 2;
    u16* wkb  = (u16*)p;  p += (size_t)D_ * D_ * 2;
    u16* wvb  = (u16*)p;  p += (size_t)D_ * D_ * 2;
    u16* wob  = (u16*)p;  p += (size_t)D_ * D_ * 2;
    float* Rl = (float*)p; p += (size_t)B_ * NH_ * L_ * 4;
    u16* ob = qpre;   // dead after LN
    u16* vt = kpre;   // dead after LN

    const int nTot8 = (M_ * D_ + 4 * D_ * D_) / 8;    // 1,081,344
    cvt_all<<<(nTot8 + 255) / 256, 256, 0, stream>>>(
        x, Wq, Wk, Wv, Wo, xb, wqb, wkb, wvb, wob);

    gemm_qkv<<<1152, 256, 0, stream>>>(
        xb, wqb, wkb, wvb, bk, bv, qpre, kpre, vb);

    ln2_bf16<<<dim3(M_, 2), 256, 0, stream>>>(qpre, kpre, gq, gk, qb, kb);

    attn_stats<<<768, 256, 0, stream>>>(qb, kb, Rl);
    transpose_v_scaled<<<dim3(L_ / 64, NH_, B_), 256, 0, stream>>>(vb, Rl, vt);
    attn_out<<<768, 256, 0, stream>>>(qb, kb, vt, ob);

    gemm_final<<<384, 256, 0, stream>>>(ob, wob, bo, x, out);
}